// Round 4
// baseline (204.430 us; speedup 1.0000x reference)
//
#include <hip/hip_runtime.h>

// SSA forward, f32 I/O:
//   q = heads(lif(bn(x Wq^T))), k = heads(lif(bn(x Wk^T))), v = heads(bn(x Wv^T))
//   o = 0.125 * q @ (k^T v)   (no softmax -> associativity), out = bn(o Wp^T)
// Q/K pre-LIF GEMMs use 3-term bf16 split (xh*wh + xl*wh + xh*wl) for ~f32
// accuracy (spike threshold is precision-critical). A stored 2-seg [xh|xl],
// W stored 3-seg [wh|wh|wl]; segment 3 re-reads xh via k-offset wrap.
// GEMM: 256x256 tile, BK=32, 8 waves (4Mx2N), 4 LDS buffers (128KB),
// prefetch depth 3 with counted vmcnt(10), A+B interleaved 128B rows with
// 3-bit XOR swizzle (both sides), 2 phases/K-tile of 16 MFMA, setprio.

#define T_ 4
#define B_ 4
#define N_ 1024
#define C_ 512
#define H_ 8
#define M_ (T_*B_*N_)   // 16384

typedef __bf16 bf16x8 __attribute__((ext_vector_type(8)));
typedef float  floatx4 __attribute__((ext_vector_type(4)));

__device__ __forceinline__ float bf2f(unsigned short u) {
  union { unsigned int i; float f; } v; v.i = ((unsigned int)u) << 16; return v.f;
}
__device__ __forceinline__ unsigned short f2bf(float f) {
  unsigned int x = __float_as_uint(f);
  return (unsigned short)((x + 0x7fffu + ((x >> 16) & 1u)) >> 16);  // RNE
}

#define GLOAD16(gaddr, ldsbase) \
  __builtin_amdgcn_global_load_lds((__attribute__((address_space(1))) void*)(gaddr), \
                                   (__attribute__((address_space(3))) void*)(ldsbase), 16, 0, 0)

// x -> 2-segment [hi | lo], row stride 1024
__global__ __launch_bounds__(256) void prep_split_x(const float* __restrict__ src,
                                                    unsigned short* __restrict__ dst,
                                                    int nelem) {
  const int idx = (blockIdx.x * 256 + threadIdx.x) * 4;
  if (idx >= nelem) return;
  const float4 v = *(const float4*)(src + idx);
  const int row = idx >> 9, k = idx & 511;
  const size_t base = (size_t)row * 1024 + k;
  float vv[4] = {v.x, v.y, v.z, v.w};
  unsigned short h[4], l[4];
#pragma unroll
  for (int j = 0; j < 4; ++j) { h[j] = f2bf(vv[j]); l[j] = f2bf(vv[j] - bf2f(h[j])); }
  *(ushort4*)(dst + base) = ushort4{h[0], h[1], h[2], h[3]};
  *(ushort4*)(dst + base + 512) = ushort4{l[0], l[1], l[2], l[3]};
}

// w -> 3-segment [hi | hi | lo], row stride 1536
__global__ __launch_bounds__(256) void prep_split_w(const float* __restrict__ src,
                                                    unsigned short* __restrict__ dst,
                                                    int nelem) {
  const int idx = (blockIdx.x * 256 + threadIdx.x) * 4;
  if (idx >= nelem) return;
  const float4 v = *(const float4*)(src + idx);
  const int row = idx >> 9, k = idx & 511;
  const size_t base = (size_t)row * 1536 + k;
  float vv[4] = {v.x, v.y, v.z, v.w};
  unsigned short h[4], l[4];
#pragma unroll
  for (int j = 0; j < 4; ++j) { h[j] = f2bf(vv[j]); l[j] = f2bf(vv[j] - bf2f(h[j])); }
  ushort4 hi{h[0], h[1], h[2], h[3]};
  *(ushort4*)(dst + base) = hi;
  *(ushort4*)(dst + base + 512) = hi;
  *(ushort4*)(dst + base + 1024) = ushort4{l[0], l[1], l[2], l[3]};
}

__global__ __launch_bounds__(256) void prep_cast(const float* __restrict__ src,
                                                 unsigned short* __restrict__ dst,
                                                 int nelem) {
  const int idx = (blockIdx.x * 256 + threadIdx.x) * 4;
  if (idx >= nelem) return;
  const float4 v = *(const float4*)(src + idx);
  *(ushort4*)(dst + idx) = ushort4{f2bf(v.x), f2bf(v.y), f2bf(v.z), f2bf(v.w)};
}

// BN scale/shift precompute: groups q,k,v,p -> scl/sft[2048]
struct BnParams { const float* p[20]; };
__global__ __launch_bounds__(256) void bn_prep(BnParams P, float* __restrict__ scl,
                                               float* __restrict__ sft) {
  const int o = blockIdx.x * 256 + threadIdx.x;  // 0..2047
  const int grp = o >> 9, ci = o & 511;
  const float* bias = P.p[grp * 5 + 0];
  const float* g    = P.p[grp * 5 + 1];
  const float* bt   = P.p[grp * 5 + 2];
  const float* mu   = P.p[grp * 5 + 3];
  const float* var  = P.p[grp * 5 + 4];
  const float s = g[ci] * rsqrtf(var[ci] + 1e-5f);
  scl[o] = s;
  sft[o] = (bias[ci] - mu[ci]) * s + bt[ci];
}

struct Job2 {
  const unsigned short* A; int lda;
  const unsigned short* w; int ldb;
  int K, ldc;
  const float* scl; const float* sft;
  float* out32; unsigned short* out16;
};

// ---------------------------------------------------------------------------
// y[m,n] = sum_k A[m,k] W[n,k] (+ BN epilogue).  See header comment.
// ---------------------------------------------------------------------------
__global__ __launch_bounds__(512, 2) void gemm_bn(Job2 j0, Job2 j1, int mode) {
  const int chunk = gridDim.x >> 3;
  const int L = (blockIdx.x & 7) * chunk + (blockIdx.x >> 3);
  Job2 job; int idx, ntile;
  if (mode == 1) {            // 2:1 interleave of j0 (4 n-tiles) and j1 (2)
    const int g = L / 3, r = L - g * 3;
    if (r < 2) { job = j0; idx = g * 2 + r; ntile = 4; }
    else       { job = j1; idx = g;         ntile = 2; }
  } else { job = j0; idx = L; ntile = 2; }
  const int panel = idx / ntile;
  const int n0 = (idx - panel * ntile) * 256;
  const int m0 = panel * 256;

  const int tid = threadIdx.x;
  const int wv = tid >> 6, lane = tid & 63;
  const int wm = wv >> 1, wn = wv & 1;          // wave tile 64 rows x 128 cols
  const int NT = job.K >> 5;

  // Combined A+B LDS tile: 256 rows x 128B (A units 0..3, B units 4..7),
  // 16B-unit u stored at position u ^ (row&7).  4 buffers = 128 KB.
  __shared__ unsigned short AB[4][256 * 64];

  // --- staging setup (per-lane): one gload = 8 combined rows x 128B
  const int rloc = lane >> 3;             // row within 8-row chunk
  const int ulog = (lane & 7) ^ rloc;     // logical unit this lane fetches
  const bool isA = ulog < 4;
  const unsigned short* bq[4];
#pragma unroll
  for (int q = 0; q < 4; ++q) {
    const int row = wv * 32 + q * 8 + rloc;
    bq[q] = isA ? job.A + (size_t)(m0 + row) * job.lda + ulog * 8
                : job.w + (size_t)(n0 + row) * job.ldb + (ulog - 4) * 8;
  }

#define ISSUE2(t_, b_, q0_, q1_) do {                                        \
    const int kB_ = (t_) * 32;                                               \
    const int kA_ = ((t_) < 32 ? (t_) : (t_) - 32) * 32;                     \
    const int off_ = isA ? kA_ : kB_;                                        \
    GLOAD16(bq[q0_] + off_, &AB[b_][(wv * 32 + (q0_) * 8) * 64]);            \
    GLOAD16(bq[q1_] + off_, &AB[b_][(wv * 32 + (q1_) * 8) * 64]);            \
  } while (0)

  // --- read setup
  const int r15 = lane & 15;
  const int apos = (lane >> 4) ^ (lane & 7);        // stored unit for A frag
  const int bpos = (4 | (lane >> 4)) ^ (lane & 7);  // stored unit for B frag
  const int aoff = (wm * 64 + r15) * 64 + apos * 8;
  const int boff = (wn * 128 + r15) * 64 + bpos * 8;

  floatx4 acc[4][8];
#pragma unroll
  for (int i = 0; i < 4; ++i)
#pragma unroll
    for (int j = 0; j < 8; ++j) acc[i][j] = floatx4{0.f, 0.f, 0.f, 0.f};

  // prologue: prefetch tiles 0,1,2
#pragma unroll
  for (int t = 0; t < 3; ++t) { ISSUE2(t, t, 0, 1); ISSUE2(t, t, 2, 3); }

  for (int kt = 0; kt < NT; ++kt) {
    const int cur = kt & 3;
    const int pre = (kt + 3) & 3;
    const bool pf = (kt + 3) < NT;
    const unsigned short* lb = &AB[cur][0];

    // ---- phase 0: issue A-ish half of prefetch, wait tile kt, MFMA j=0..3
    if (pf) {
      ISSUE2(kt + 3, pre, 0, 1);
      asm volatile("s_waitcnt vmcnt(10)" ::: "memory");
    } else {
      const int rem = NT - 1 - kt;
      if (rem == 2)      asm volatile("s_waitcnt vmcnt(8)" ::: "memory");
      else if (rem == 1) asm volatile("s_waitcnt vmcnt(4)" ::: "memory");
      else               asm volatile("s_waitcnt vmcnt(0)" ::: "memory");
    }
    __builtin_amdgcn_s_barrier();

    bf16x8 a[4], bfr[4];
#pragma unroll
    for (int i = 0; i < 4; ++i) a[i] = *(const bf16x8*)(lb + aoff + i * 1024);
#pragma unroll
    for (int j = 0; j < 4; ++j) bfr[j] = *(const bf16x8*)(lb + boff + j * 1024);
    asm volatile("s_waitcnt lgkmcnt(0)" ::: "memory");
    __builtin_amdgcn_sched_barrier(0);
    __builtin_amdgcn_s_setprio(1);
#pragma unroll
    for (int i = 0; i < 4; ++i)
#pragma unroll
      for (int j = 0; j < 4; ++j)
        acc[i][j] = __builtin_amdgcn_mfma_f32_16x16x32_bf16(a[i], bfr[j], acc[i][j], 0, 0, 0);
    __builtin_amdgcn_s_setprio(0);
    __builtin_amdgcn_s_barrier();

    // ---- phase 1: issue rest of prefetch, MFMA j=4..7
    if (pf) ISSUE2(kt + 3, pre, 2, 3);
#pragma unroll
    for (int j = 0; j < 4; ++j) bfr[j] = *(const bf16x8*)(lb + boff + (4 + j) * 1024);
    asm volatile("s_waitcnt lgkmcnt(0)" ::: "memory");
    __builtin_amdgcn_sched_barrier(0);
    __builtin_amdgcn_s_setprio(1);
#pragma unroll
    for (int i = 0; i < 4; ++i)
#pragma unroll
      for (int j = 0; j < 4; ++j)
        acc[i][4 + j] = __builtin_amdgcn_mfma_f32_16x16x32_bf16(a[i], bfr[j], acc[i][4 + j], 0, 0, 0);
    __builtin_amdgcn_s_setprio(0);
    __builtin_amdgcn_s_barrier();
  }

  // ---- epilogue: BN affine, write
  float scl[8], sft[8];
#pragma unroll
  for (int j = 0; j < 8; ++j) {
    const int c = n0 + wn * 128 + j * 16 + r15;
    scl[j] = job.scl[c];
    sft[j] = job.sft[c];
  }
  const int rbase = m0 + wm * 64 + (lane >> 4) * 4;
#pragma unroll
  for (int i = 0; i < 4; ++i) {
#pragma unroll
    for (int r = 0; r < 4; ++r) {
      const size_t mrow = (size_t)(rbase + 16 * i + r) * job.ldc;
#pragma unroll
      for (int j = 0; j < 8; ++j) {
        const int c = n0 + wn * 128 + j * 16 + r15;
        const float val = acc[i][j][r] * scl[j] + sft[j];
        if (job.out32) job.out32[mrow + c] = val;
        else           job.out16[mrow + c] = f2bf(val);
      }
    }
  }
}

// ---------------------------------------------------------------------------
// LIF (T-sequential, hard threshold >= 1, reset to 0) for q,k + transposes.
// yqk is [m][1024] f32 (q cols 0..511, k cols 512..1023).
// ---------------------------------------------------------------------------
__global__ __launch_bounds__(256) void lif_transpose(
    const float* __restrict__ yqk, const unsigned short* __restrict__ yv,
    unsigned short* __restrict__ qs, unsigned short* __restrict__ ktr,
    unsigned short* __restrict__ vtr) {
  const int c0 = blockIdx.x * 64, n0 = blockIdx.y * 64, b = blockIdx.z;
  const int tid = threadIdx.x;
  const int cl = tid & 63;
  const int nr = tid >> 6;

  __shared__ unsigned short tile[64][65];

  float vq[16], vk[16];
#pragma unroll
  for (int i = 0; i < 16; ++i) { vq[i] = 0.f; vk[i] = 0.f; }

  for (int t = 0; t < T_; ++t) {
    const size_t qk_base = (((size_t)t * B_ + b) * N_ + n0) * 1024 + c0;
    const size_t base    = (((size_t)t * B_ + b) * N_ + n0) * C_ + c0;
    const size_t tbase   = (((size_t)t * B_ + b) * C_ + c0) * N_ + n0;
#pragma unroll
    for (int i = 0; i < 16; ++i) {
      const float y = yqk[qk_base + (size_t)(nr + 4 * i) * 1024 + cl];
      vq[i] += (y - vq[i]) * 0.5f;
      const bool sp = vq[i] >= 1.0f;
      qs[base + (size_t)(nr + 4 * i) * C_ + cl] = sp ? (unsigned short)0x3F80 : (unsigned short)0;
      if (sp) vq[i] = 0.f;
    }
#pragma unroll
    for (int i = 0; i < 16; ++i) {
      const float y = yqk[qk_base + (size_t)(nr + 4 * i) * 1024 + 512 + cl];
      vk[i] += (y - vk[i]) * 0.5f;
      const bool sp = vk[i] >= 1.0f;
      tile[nr + 4 * i][cl] = sp ? (unsigned short)0x3F80 : (unsigned short)0;
      if (sp) vk[i] = 0.f;
    }
    __syncthreads();
#pragma unroll
    for (int i = 0; i < 16; ++i)
      ktr[tbase + (size_t)(nr + 4 * i) * N_ + cl] = tile[cl][nr + 4 * i];
    __syncthreads();
#pragma unroll
    for (int i = 0; i < 16; ++i)
      tile[nr + 4 * i][cl] = yv[base + (size_t)(nr + 4 * i) * C_ + cl];
    __syncthreads();
#pragma unroll
    for (int i = 0; i < 16; ++i)
      vtr[tbase + (size_t)(nr + 4 * i) * N_ + cl] = tile[cl][nr + 4 * i];
    __syncthreads();
  }
}

// ---------------------------------------------------------------------------
__global__ __launch_bounds__(256) void kv_gemm(const unsigned short* __restrict__ ktr,
                                               const unsigned short* __restrict__ vtr,
                                               float* __restrict__ kvp) {
  const int bid = blockIdx.x;
  const int head = bid >> 1;
  const int mh = bid & 1;
  const int tb = head >> 3;
  const int h = head & 7;
  const int wv = threadIdx.x >> 6, lane = threadIdx.x & 63;
  const int m0 = mh * 512 + wv * 128;
  const size_t cbase = (size_t)tb * C_ + h * 64;
  const int rsel = lane & 15, koff = (lane >> 4) * 8;

  floatx4 acc[4][4];
#pragma unroll
  for (int i = 0; i < 4; ++i)
#pragma unroll
    for (int j = 0; j < 4; ++j) acc[i][j] = floatx4{0.f, 0.f, 0.f, 0.f};

#pragma unroll
  for (int s = 0; s < 4; ++s) {
    const int m = m0 + s * 32 + koff;
    bf16x8 a[4], b[4];
#pragma unroll
    for (int dt = 0; dt < 4; ++dt)
      a[dt] = *(const bf16x8*)(ktr + (cbase + dt * 16 + rsel) * N_ + m);
#pragma unroll
    for (int et = 0; et < 4; ++et)
      b[et] = *(const bf16x8*)(vtr + (cbase + et * 16 + rsel) * N_ + m);
#pragma unroll
    for (int dt = 0; dt < 4; ++dt)
#pragma unroll
      for (int et = 0; et < 4; ++et)
        acc[dt][et] = __builtin_amdgcn_mfma_f32_16x16x32_bf16(a[dt], b[et], acc[dt][et], 0, 0, 0);
  }

  float* outp = kvp + ((size_t)head * 8 + mh * 4 + wv) * 4096;
  const int dbase = (lane >> 4) * 4;
  const int e0 = lane & 15;
#pragma unroll
  for (int dt = 0; dt < 4; ++dt)
#pragma unroll
    for (int et = 0; et < 4; ++et)
#pragma unroll
      for (int r = 0; r < 4; ++r)
        outp[(dt * 16 + dbase + r) * 64 + et * 16 + e0] = acc[dt][et][r];
}

__global__ __launch_bounds__(256) void kv_reduce(const float* __restrict__ kvp,
                                                 unsigned short* __restrict__ kvt) {
  const int gid = blockIdx.x * 256 + threadIdx.x;
  const int idx4 = gid * 4;
  const int head = idx4 >> 12;
  const int rem = idx4 & 4095;
  const int e = rem >> 6, d0 = rem & 63;
  const float* p = kvp + (size_t)head * 8 * 4096;
  unsigned short rr[4];
#pragma unroll
  for (int j = 0; j < 4; ++j) {
    float s = 0.f;
#pragma unroll
    for (int pp = 0; pp < 8; ++pp) s += p[pp * 4096 + (d0 + j) * 64 + e];
    rr[j] = f2bf(0.125f * s);
  }
  uint2 o;
  o.x = (unsigned)rr[0] | ((unsigned)rr[1] << 16);
  o.y = (unsigned)rr[2] | ((unsigned)rr[3] << 16);
  *(uint2*)(kvt + idx4) = o;
}

__global__ __launch_bounds__(256) void av_gemm(const unsigned short* __restrict__ qs,
                                               const unsigned short* __restrict__ kvt,
                                               unsigned short* __restrict__ obuf) {
  const int bx = blockIdx.x;
  const int tb = bx >> 3, nt = bx & 7;
  const int wv = threadIdx.x >> 6, lane = threadIdx.x & 63;
  const int n0 = nt * 128 + wv * 32;
  const int rsel = lane & 15, koff = (lane >> 4) * 8;
  const size_t qbase = ((size_t)tb * N_ + n0) * C_;

#pragma unroll 1
  for (int h = 0; h < H_; ++h) {
    floatx4 acc[2][4];
#pragma unroll
    for (int i = 0; i < 2; ++i)
#pragma unroll
      for (int j = 0; j < 4; ++j) acc[i][j] = floatx4{0.f, 0.f, 0.f, 0.f};
    const unsigned short* kvh = kvt + ((size_t)tb * 8 + h) * 4096;
#pragma unroll
    for (int s = 0; s < 2; ++s) {
      bf16x8 a[2], b[4];
#pragma unroll
      for (int i = 0; i < 2; ++i)
        a[i] = *(const bf16x8*)(qs + qbase + (size_t)(i * 16 + rsel) * C_ + h * 64 + s * 32 + koff);
#pragma unroll
      for (int et = 0; et < 4; ++et)
        b[et] = *(const bf16x8*)(kvh + (et * 16 + rsel) * 64 + s * 32 + koff);
#pragma unroll
      for (int i = 0; i < 2; ++i)
#pragma unroll
        for (int et = 0; et < 4; ++et)
          acc[i][et] = __builtin_amdgcn_mfma_f32_16x16x32_bf16(a[i], b[et], acc[i][et], 0, 0, 0);
    }
#pragma unroll
    for (int i = 0; i < 2; ++i)
#pragma unroll
      for (int et = 0; et < 4; ++et)
#pragma unroll
        for (int r = 0; r < 4; ++r) {
          const int n = n0 + i * 16 + (lane >> 4) * 4 + r;
          obuf[((size_t)tb * N_ + n) * C_ + h * 64 + et * 16 + rsel] = f2bf(acc[i][et][r]);
        }
  }
}

// ---------------------------------------------------------------------------
extern "C" void kernel_launch(void* const* d_in, const int* in_sizes, int n_in,
                              void* d_out, int out_size, void* d_ws, size_t ws_size,
                              hipStream_t stream) {
  const float* x  = (const float*)d_in[0];
  const float* qw = (const float*)d_in[2];
  const float* kw = (const float*)d_in[8];
  const float* vw = (const float*)d_in[14];
  const float* pw = (const float*)d_in[20];

  char* ws = (char*)d_ws;
  unsigned short* X2   = (unsigned short*)(ws + 0);            // 32 MB [16384][1024]
  unsigned short* Wqk3 = (unsigned short*)(ws + 33554432ull);  // 3 MB  [1024][1536]
  unsigned short* Wvb  = (unsigned short*)(ws + 36700160ull);  // 0.5 MB
  float*          yqk  = (float*)(ws + 50331648ull);           // 64 MB [16384][1024]
  unsigned short* yv   = (unsigned short*)(ws + 117440512ull); // 16 MB
  unsigned short* Wpb  = (unsigned short*)(ws + 134217728ull); // 0.5 MB (live to end)
  float*          scl  = (float*)(ws + 134742016ull);          // 8 KB [2048]
  float*          sft  = (float*)(ws + 134750208ull);          // 8 KB
  // after QKV gemm (X2/W dead):
  unsigned short* qsb = (unsigned short*)(ws + 0);             // 16 MB
  unsigned short* ktb = (unsigned short*)(ws + 16777216ull);   // 16 MB
  unsigned short* vtb = (unsigned short*)(ws + 33554432ull);   // 16 MB
  // after lif (yqk dead):
  float*          kvp = (float*)(ws + 50331648ull);            // 16 MB
  unsigned short* kvt = (unsigned short*)(ws + 67108864ull);   // 1 MB
  unsigned short* ob  = (unsigned short*)(ws + 68157440ull);   // 16 MB

  prep_split_x<<<dim3(M_ * C_ / 4 / 256), 256, 0, stream>>>(x, X2, M_ * C_);
  prep_split_w<<<dim3(C_ * C_ / 4 / 256), 256, 0, stream>>>(qw, Wqk3, C_ * C_);
  prep_split_w<<<dim3(C_ * C_ / 4 / 256), 256, 0, stream>>>(kw, Wqk3 + 512 * 1536, C_ * C_);
  prep_cast<<<dim3(C_ * C_ / 4 / 256), 256, 0, stream>>>(vw, Wvb, C_ * C_);
  prep_cast<<<dim3(C_ * C_ / 4 / 256), 256, 0, stream>>>(pw, Wpb, C_ * C_);

  BnParams bp;
  bp.p[0]=(const float*)d_in[3];  bp.p[1]=(const float*)d_in[4];  bp.p[2]=(const float*)d_in[5];  bp.p[3]=(const float*)d_in[6];  bp.p[4]=(const float*)d_in[7];
  bp.p[5]=(const float*)d_in[9];  bp.p[6]=(const float*)d_in[10]; bp.p[7]=(const float*)d_in[11]; bp.p[8]=(const float*)d_in[12]; bp.p[9]=(const float*)d_in[13];
  bp.p[10]=(const float*)d_in[15];bp.p[11]=(const float*)d_in[16];bp.p[12]=(const float*)d_in[17];bp.p[13]=(const float*)d_in[18];bp.p[14]=(const float*)d_in[19];
  bp.p[15]=(const float*)d_in[21];bp.p[16]=(const float*)d_in[22];bp.p[17]=(const float*)d_in[23];bp.p[18]=(const float*)d_in[24];bp.p[19]=(const float*)d_in[25];
  bn_prep<<<dim3(8), 256, 0, stream>>>(bp, scl, sft);

  Job2 jqk{X2, 1024, Wqk3, 1536, 1536, 1024, scl, sft, yqk, nullptr};
  Job2 jv {X2, 1024, Wvb,  512,  512,  512,  scl + 1024, sft + 1024, nullptr, yv};
  gemm_bn<<<dim3(384), 512, 0, stream>>>(jqk, jv, 1);

  lif_transpose<<<dim3(C_ / 64, N_ / 64, B_), 256, 0, stream>>>(yqk, yv, qsb, ktb, vtb);

  kv_gemm<<<dim3(256), 256, 0, stream>>>(ktb, vtb, kvp);
  kv_reduce<<<dim3(512), 256, 0, stream>>>(kvp, kvt);
  av_gemm<<<dim3(128), 256, 0, stream>>>(qsb, kvt, ob);

  Job2 jp{ob, 512, Wpb, 512, 512, 512, scl + 1536, sft + 1536, (float*)d_out, nullptr};
  gemm_bn<<<dim3(128), 512, 0, stream>>>(jp, jp, 0);
}

// Round 5
// 170.971 us; speedup vs baseline: 1.1957x; 1.1957x over previous
//
#include <hip/hip_runtime.h>

// SSA forward, f32 I/O:
//   q = heads(lif(bn(x Wq^T))), k = heads(lif(bn(x Wk^T))), v = heads(bn(x Wv^T))
//   o = 0.125 * q @ (k^T v)   (no softmax -> associativity), out = bn(o Wp^T)
// Q/K pre-LIF GEMMs use 3-term bf16 split (xh*wh + xl*wh + xh*wl) for ~f32
// accuracy (spike threshold is precision-critical). A stored 2-seg [xh|xl],
// W stored 3-seg [wh|wh|wl]; segment 3 re-reads xh via k-offset wrap.
// GEMM: 256x256 tile, BK=32, 8 waves (4Mx2N), 4 LDS buffers (128KB),
// REGISTER-PIPELINED: each slot reads next tile's frags while MFMAing the
// current tile's (ds_read -> use distance = 1 phase). One counted-vmcnt
// barrier per K-tile; never drains mid-loop. XCD panel colocation.

#define T_ 4
#define B_ 4
#define N_ 1024
#define C_ 512
#define H_ 8
#define M_ (T_*B_*N_)   // 16384

typedef __bf16 bf16x8 __attribute__((ext_vector_type(8)));
typedef float  floatx4 __attribute__((ext_vector_type(4)));

__device__ __forceinline__ float bf2f(unsigned short u) {
  union { unsigned int i; float f; } v; v.i = ((unsigned int)u) << 16; return v.f;
}
__device__ __forceinline__ unsigned short f2bf(float f) {
  unsigned int x = __float_as_uint(f);
  return (unsigned short)((x + 0x7fffu + ((x >> 16) & 1u)) >> 16);  // RNE
}

#define GLOAD16(gaddr, ldsbase) \
  __builtin_amdgcn_global_load_lds((__attribute__((address_space(1))) void*)(gaddr), \
                                   (__attribute__((address_space(3))) void*)(ldsbase), 16, 0, 0)

// x -> 2-segment [hi | lo], row stride 1024
__global__ __launch_bounds__(256) void prep_split_x(const float* __restrict__ src,
                                                    unsigned short* __restrict__ dst,
                                                    int nelem) {
  const int idx = (blockIdx.x * 256 + threadIdx.x) * 4;
  if (idx >= nelem) return;
  const float4 v = *(const float4*)(src + idx);
  const int row = idx >> 9, k = idx & 511;
  const size_t base = (size_t)row * 1024 + k;
  float vv[4] = {v.x, v.y, v.z, v.w};
  unsigned short h[4], l[4];
#pragma unroll
  for (int j = 0; j < 4; ++j) { h[j] = f2bf(vv[j]); l[j] = f2bf(vv[j] - bf2f(h[j])); }
  *(ushort4*)(dst + base) = ushort4{h[0], h[1], h[2], h[3]};
  *(ushort4*)(dst + base + 512) = ushort4{l[0], l[1], l[2], l[3]};
}

// all weight preps in one launch: z=0 qw->Wqk3[0:512], z=1 kw->Wqk3[512:1024]
// (3-seg [hi|hi|lo], stride 1536); z=2 vw->cast; z=3 pw->cast
__global__ __launch_bounds__(256) void prep_weights(const float* __restrict__ qw,
                                                    const float* __restrict__ kw,
                                                    const float* __restrict__ vw,
                                                    const float* __restrict__ pw,
                                                    unsigned short* __restrict__ Wqk3,
                                                    unsigned short* __restrict__ Wvb,
                                                    unsigned short* __restrict__ Wpb) {
  const int z = blockIdx.z;
  const int idx = (blockIdx.x * 256 + threadIdx.x) * 4;
  if (idx >= C_ * C_) return;
  const float* src = (z == 0) ? qw : (z == 1) ? kw : (z == 2) ? vw : pw;
  const float4 v = *(const float4*)(src + idx);
  if (z >= 2) {
    unsigned short* dst = (z == 2) ? Wvb : Wpb;
    *(ushort4*)(dst + idx) = ushort4{f2bf(v.x), f2bf(v.y), f2bf(v.z), f2bf(v.w)};
    return;
  }
  const int row = idx >> 9, k = idx & 511;
  unsigned short* dst = Wqk3 + (size_t)(z * 512) * 1536;
  const size_t base = (size_t)row * 1536 + k;
  float vv[4] = {v.x, v.y, v.z, v.w};
  unsigned short h[4], l[4];
#pragma unroll
  for (int j = 0; j < 4; ++j) { h[j] = f2bf(vv[j]); l[j] = f2bf(vv[j] - bf2f(h[j])); }
  ushort4 hi{h[0], h[1], h[2], h[3]};
  *(ushort4*)(dst + base) = hi;
  *(ushort4*)(dst + base + 512) = hi;
  *(ushort4*)(dst + base + 1024) = ushort4{l[0], l[1], l[2], l[3]};
}

// BN scale/shift precompute: groups q,k,v,p -> scl/sft[2048]
struct BnParams { const float* p[20]; };
__global__ __launch_bounds__(256) void bn_prep(BnParams P, float* __restrict__ scl,
                                               float* __restrict__ sft) {
  const int o = blockIdx.x * 256 + threadIdx.x;  // 0..2047
  const int grp = o >> 9, ci = o & 511;
  const float* bias = P.p[grp * 5 + 0];
  const float* g    = P.p[grp * 5 + 1];
  const float* bt   = P.p[grp * 5 + 2];
  const float* mu   = P.p[grp * 5 + 3];
  const float* var  = P.p[grp * 5 + 4];
  const float s = g[ci] * rsqrtf(var[ci] + 1e-5f);
  scl[o] = s;
  sft[o] = (bias[ci] - mu[ci]) * s + bt[ci];
}

struct Job2 {
  const unsigned short* A; int lda;
  const unsigned short* w; int ldb;
  int K, ldc;
  const float* scl; const float* sft;
  float* out32; unsigned short* out16;
};

// ---------------------------------------------------------------------------
// y[m,n] = sum_k A[m,k] W[n,k] (+ BN epilogue).  See header comment.
// grid: npanels*ntile blocks, 1/CU; XCD colocation: panel-mates same XCD.
// ---------------------------------------------------------------------------
__global__ __launch_bounds__(512, 2) void gemm_bn(Job2 job, int lntile) {
  const int xcd = blockIdx.x & 7, slot = blockIdx.x >> 3;
  const int ntm1 = (1 << lntile) - 1;
  const int panel = xcd + 8 * (slot >> lntile);
  const int m0 = panel * 256;
  const int n0 = (slot & ntm1) * 256;

  const int tid = threadIdx.x;
  const int wv = tid >> 6, lane = tid & 63;
  const int wm = wv >> 1, wn = wv & 1;          // wave tile 64 rows x 128 cols
  const int NT = job.K >> 5;                    // K-tiles of 32

  // Combined A+B LDS tile: 256 rows x 128B (A units 0..3, B units 4..7),
  // 16B-unit u stored at position u ^ (row&7).  4 buffers = 128 KB.
  __shared__ unsigned short AB[4][256 * 64];

  // --- staging (per-lane): one gload = 8 combined rows x 128B, linear dest
  const int rloc = lane >> 3;             // row within 8-row chunk
  const int ulog = (lane & 7) ^ rloc;     // logical 16B unit this lane fetches
  const bool isA = ulog < 4;
  const unsigned short* bq[4];
#pragma unroll
  for (int q = 0; q < 4; ++q) {
    const int row = wv * 32 + q * 8 + rloc;
    bq[q] = isA ? job.A + (size_t)(m0 + row) * job.lda + ulog * 8
                : job.w + (size_t)(n0 + row) * job.ldb + (ulog - 4) * 8;
  }

#define ISSUE(T_, BUF_) do {                                                 \
    const int t_ = (T_);                                                     \
    const int off_ = isA ? ((t_ < 32 ? t_ : t_ - 32) << 5) : (t_ << 5);      \
    _Pragma("unroll")                                                        \
    for (int q = 0; q < 4; ++q)                                              \
      GLOAD16(bq[q] + off_, &AB[BUF_][(wv * 32 + q * 8) * 64]);              \
  } while (0)

  // --- fragment reads
  const int r15 = lane & 15;
  const int apos = (lane >> 4) ^ (lane & 7);        // stored unit for A frag
  const int bpos = (4 | (lane >> 4)) ^ (lane & 7);  // stored unit for B frag
  const int aoff = (wm * 64 + r15) * 64 + apos * 8;
  const int boff = (wn * 128 + r15) * 64 + bpos * 8;

  bf16x8 A0[4], A1[4], L0[4], L1[4], Hh[4];

#define RD_ALO(BUF_, AX, LX) do {                                            \
    const unsigned short* lb_ = &AB[BUF_][0];                                \
    _Pragma("unroll")                                                        \
    for (int i_ = 0; i_ < 4; ++i_) AX[i_] = *(const bf16x8*)(lb_ + aoff + i_ * 1024); \
    _Pragma("unroll")                                                        \
    for (int j_ = 0; j_ < 4; ++j_) LX[j_] = *(const bf16x8*)(lb_ + boff + j_ * 1024); \
  } while (0)

#define RD_HI(BUF_) do {                                                     \
    const unsigned short* lb_ = &AB[BUF_][0];                                \
    _Pragma("unroll")                                                        \
    for (int j_ = 0; j_ < 4; ++j_) Hh[j_] = *(const bf16x8*)(lb_ + boff + (4 + j_) * 1024); \
  } while (0)

#define MF_LO(AX, LX) do {                                                   \
    __builtin_amdgcn_s_setprio(1);                                           \
    _Pragma("unroll")                                                        \
    for (int i_ = 0; i_ < 4; ++i_)                                           \
    _Pragma("unroll")                                                        \
      for (int j_ = 0; j_ < 4; ++j_)                                         \
        acc[i_][j_] = __builtin_amdgcn_mfma_f32_16x16x32_bf16(AX[i_], LX[j_], acc[i_][j_], 0, 0, 0); \
    __builtin_amdgcn_s_setprio(0);                                           \
  } while (0)

#define MF_HI(AX) do {                                                       \
    __builtin_amdgcn_s_setprio(1);                                           \
    _Pragma("unroll")                                                        \
    for (int i_ = 0; i_ < 4; ++i_)                                           \
    _Pragma("unroll")                                                        \
      for (int j_ = 0; j_ < 4; ++j_)                                         \
        acc[i_][4 + j_] = __builtin_amdgcn_mfma_f32_16x16x32_bf16(AX[i_], Hh[j_], acc[i_][4 + j_], 0, 0, 0); \
    __builtin_amdgcn_s_setprio(0);                                           \
  } while (0)

#define MIDBAR(N_) do {                                                      \
    asm volatile("s_waitcnt vmcnt(" #N_ ")" ::: "memory");                   \
    __builtin_amdgcn_s_barrier();                                            \
    __builtin_amdgcn_sched_barrier(0);                                       \
  } while (0)

// slot kt: phase0 {read Bhi(kt), MFMA A(kt)xBlo(kt)} | vmcnt+bar |
//          phase1 {issue(kt+3), read A,Blo(kt+1), MFMA A(kt)xBhi(kt)}
#define SLOT_I(KT_, BC_, BN_, AX, LX, AY, LY) do {                           \
    RD_HI(BC_); MF_LO(AX, LX);                                               \
    MIDBAR(4);                                                               \
    ISSUE((KT_) + 3, (BC_ + 3) & 3);                                         \
    RD_ALO(BN_, AY, LY); MF_HI(AX);                                          \
  } while (0)

  floatx4 acc[4][8];
#pragma unroll
  for (int i = 0; i < 4; ++i)
#pragma unroll
    for (int j = 0; j < 8; ++j) acc[i][j] = floatx4{0.f, 0.f, 0.f, 0.f};

  // prologue: stage tiles 0,1,2; ensure 0,1 done; load frags(0)
  ISSUE(0, 0); ISSUE(1, 1); ISSUE(2, 2);
  asm volatile("s_waitcnt vmcnt(4)" ::: "memory");
  __builtin_amdgcn_s_barrier();
  __builtin_amdgcn_sched_barrier(0);
  RD_ALO(0, A0, L0);

  const int NG = (NT - 4) >> 2;
  for (int g = 0; g < NG; ++g) {
    const int g4 = g << 2;
    SLOT_I(g4 + 0, 0, 1, A0, L0, A1, L1);
    SLOT_I(g4 + 1, 1, 2, A1, L1, A0, L0);
    SLOT_I(g4 + 2, 2, 3, A0, L0, A1, L1);
    SLOT_I(g4 + 3, 3, 0, A1, L1, A0, L0);
  }
  // tail: kt = NT-4 .. NT-1
  SLOT_I(NT - 4, 0, 1, A0, L0, A1, L1);                // issues NT-1
  RD_HI(1); MF_LO(A1, L1); MIDBAR(4); RD_ALO(2, A0, L0); MF_HI(A1);  // NT-3
  RD_HI(2); MF_LO(A0, L0); MIDBAR(0); RD_ALO(3, A1, L1); MF_HI(A0);  // NT-2
  RD_HI(3); MF_LO(A1, L1); MF_HI(A1);                                 // NT-1

  // ---- epilogue: BN affine, write
  float scl[8], sft[8];
#pragma unroll
  for (int j = 0; j < 8; ++j) {
    const int c = n0 + wn * 128 + j * 16 + r15;
    scl[j] = job.scl[c];
    sft[j] = job.sft[c];
  }
  const int rbase = m0 + wm * 64 + (lane >> 4) * 4;
#pragma unroll
  for (int i = 0; i < 4; ++i) {
#pragma unroll
    for (int r = 0; r < 4; ++r) {
      const size_t mrow = (size_t)(rbase + 16 * i + r) * job.ldc;
#pragma unroll
      for (int j = 0; j < 8; ++j) {
        const int c = n0 + wn * 128 + j * 16 + r15;
        const float val = acc[i][j][r] * scl[j] + sft[j];
        if (job.out32) job.out32[mrow + c] = val;
        else           job.out16[mrow + c] = f2bf(val);
      }
    }
  }
}

// ---------------------------------------------------------------------------
// LIF (T-sequential, hard threshold >= 1, reset to 0) for q,k + transposes.
// yqk is [m][1024] f32 (q cols 0..511, k cols 512..1023).
// ---------------------------------------------------------------------------
__global__ __launch_bounds__(256) void lif_transpose(
    const float* __restrict__ yqk, const unsigned short* __restrict__ yv,
    unsigned short* __restrict__ qs, unsigned short* __restrict__ ktr,
    unsigned short* __restrict__ vtr) {
  const int c0 = blockIdx.x * 64, n0 = blockIdx.y * 64, b = blockIdx.z;
  const int tid = threadIdx.x;
  const int cl = tid & 63;
  const int nr = tid >> 6;

  __shared__ unsigned short tile[64][65];

  float vq[16], vk[16];
#pragma unroll
  for (int i = 0; i < 16; ++i) { vq[i] = 0.f; vk[i] = 0.f; }

  for (int t = 0; t < T_; ++t) {
    const size_t qk_base = (((size_t)t * B_ + b) * N_ + n0) * 1024 + c0;
    const size_t base    = (((size_t)t * B_ + b) * N_ + n0) * C_ + c0;
    const size_t tbase   = (((size_t)t * B_ + b) * C_ + c0) * N_ + n0;
#pragma unroll
    for (int i = 0; i < 16; ++i) {
      const float y = yqk[qk_base + (size_t)(nr + 4 * i) * 1024 + cl];
      vq[i] += (y - vq[i]) * 0.5f;
      const bool sp = vq[i] >= 1.0f;
      qs[base + (size_t)(nr + 4 * i) * C_ + cl] = sp ? (unsigned short)0x3F80 : (unsigned short)0;
      if (sp) vq[i] = 0.f;
    }
#pragma unroll
    for (int i = 0; i < 16; ++i) {
      const float y = yqk[qk_base + (size_t)(nr + 4 * i) * 1024 + 512 + cl];
      vk[i] += (y - vk[i]) * 0.5f;
      const bool sp = vk[i] >= 1.0f;
      tile[nr + 4 * i][cl] = sp ? (unsigned short)0x3F80 : (unsigned short)0;
      if (sp) vk[i] = 0.f;
    }
    __syncthreads();
#pragma unroll
    for (int i = 0; i < 16; ++i)
      ktr[tbase + (size_t)(nr + 4 * i) * N_ + cl] = tile[cl][nr + 4 * i];
    __syncthreads();
#pragma unroll
    for (int i = 0; i < 16; ++i)
      tile[nr + 4 * i][cl] = yv[base + (size_t)(nr + 4 * i) * C_ + cl];
    __syncthreads();
#pragma unroll
    for (int i = 0; i < 16; ++i)
      vtr[tbase + (size_t)(nr + 4 * i) * N_ + cl] = tile[cl][nr + 4 * i];
    __syncthreads();
  }
}

// ---------------------------------------------------------------------------
__global__ __launch_bounds__(256) void kv_gemm(const unsigned short* __restrict__ ktr,
                                               const unsigned short* __restrict__ vtr,
                                               float* __restrict__ kvp) {
  const int bid = blockIdx.x;
  const int head = bid >> 1;
  const int mh = bid & 1;
  const int tb = head >> 3;
  const int h = head & 7;
  const int wv = threadIdx.x >> 6, lane = threadIdx.x & 63;
  const int m0 = mh * 512 + wv * 128;
  const size_t cbase = (size_t)tb * C_ + h * 64;
  const int rsel = lane & 15, koff = (lane >> 4) * 8;

  floatx4 acc[4][4];
#pragma unroll
  for (int i = 0; i < 4; ++i)
#pragma unroll
    for (int j = 0; j < 4; ++j) acc[i][j] = floatx4{0.f, 0.f, 0.f, 0.f};

#pragma unroll
  for (int s = 0; s < 4; ++s) {
    const int m = m0 + s * 32 + koff;
    bf16x8 a[4], b[4];
#pragma unroll
    for (int dt = 0; dt < 4; ++dt)
      a[dt] = *(const bf16x8*)(ktr + (cbase + dt * 16 + rsel) * N_ + m);
#pragma unroll
    for (int et = 0; et < 4; ++et)
      b[et] = *(const bf16x8*)(vtr + (cbase + et * 16 + rsel) * N_ + m);
#pragma unroll
    for (int dt = 0; dt < 4; ++dt)
#pragma unroll
      for (int et = 0; et < 4; ++et)
        acc[dt][et] = __builtin_amdgcn_mfma_f32_16x16x32_bf16(a[dt], b[et], acc[dt][et], 0, 0, 0);
  }

  float* outp = kvp + ((size_t)head * 8 + mh * 4 + wv) * 4096;
  const int dbase = (lane >> 4) * 4;
  const int e0 = lane & 15;
#pragma unroll
  for (int dt = 0; dt < 4; ++dt)
#pragma unroll
    for (int et = 0; et < 4; ++et)
#pragma unroll
      for (int r = 0; r < 4; ++r)
        outp[(dt * 16 + dbase + r) * 64 + et * 16 + e0] = acc[dt][et][r];
}

__global__ __launch_bounds__(256) void kv_reduce(const float* __restrict__ kvp,
                                                 unsigned short* __restrict__ kvt) {
  const int gid = blockIdx.x * 256 + threadIdx.x;
  const int idx4 = gid * 4;
  const int head = idx4 >> 12;
  const int rem = idx4 & 4095;
  const int e = rem >> 6, d0 = rem & 63;
  const float* p = kvp + (size_t)head * 8 * 4096;
  unsigned short rr[4];
#pragma unroll
  for (int j = 0; j < 4; ++j) {
    float s = 0.f;
#pragma unroll
    for (int pp = 0; pp < 8; ++pp) s += p[pp * 4096 + (d0 + j) * 64 + e];
    rr[j] = f2bf(0.125f * s);
  }
  uint2 o;
  o.x = (unsigned)rr[0] | ((unsigned)rr[1] << 16);
  o.y = (unsigned)rr[2] | ((unsigned)rr[3] << 16);
  *(uint2*)(kvt + idx4) = o;
}

__global__ __launch_bounds__(256) void av_gemm(const unsigned short* __restrict__ qs,
                                               const unsigned short* __restrict__ kvt,
                                               unsigned short* __restrict__ obuf) {
  const int bx = blockIdx.x;
  const int tb = bx >> 3, nt = bx & 7;
  const int wv = threadIdx.x >> 6, lane = threadIdx.x & 63;
  const int n0 = nt * 128 + wv * 32;
  const int rsel = lane & 15, koff = (lane >> 4) * 8;
  const size_t qbase = ((size_t)tb * N_ + n0) * C_;

#pragma unroll 1
  for (int h = 0; h < H_; ++h) {
    floatx4 acc[2][4];
#pragma unroll
    for (int i = 0; i < 2; ++i)
#pragma unroll
      for (int j = 0; j < 4; ++j) acc[i][j] = floatx4{0.f, 0.f, 0.f, 0.f};
    const unsigned short* kvh = kvt + ((size_t)tb * 8 + h) * 4096;
#pragma unroll
    for (int s = 0; s < 2; ++s) {
      bf16x8 a[2], b[4];
#pragma unroll
      for (int i = 0; i < 2; ++i)
        a[i] = *(const bf16x8*)(qs + qbase + (size_t)(i * 16 + rsel) * C_ + h * 64 + s * 32 + koff);
#pragma unroll
      for (int et = 0; et < 4; ++et)
        b[et] = *(const bf16x8*)(kvh + (et * 16 + rsel) * 64 + s * 32 + koff);
#pragma unroll
      for (int i = 0; i < 2; ++i)
#pragma unroll
        for (int et = 0; et < 4; ++et)
          acc[i][et] = __builtin_amdgcn_mfma_f32_16x16x32_bf16(a[i], b[et], acc[i][et], 0, 0, 0);
    }
#pragma unroll
    for (int i = 0; i < 2; ++i)
#pragma unroll
      for (int et = 0; et < 4; ++et)
#pragma unroll
        for (int r = 0; r < 4; ++r) {
          const int n = n0 + i * 16 + (lane >> 4) * 4 + r;
          obuf[((size_t)tb * N_ + n) * C_ + h * 64 + et * 16 + rsel] = f2bf(acc[i][et][r]);
        }
  }
}

// ---------------------------------------------------------------------------
extern "C" void kernel_launch(void* const* d_in, const int* in_sizes, int n_in,
                              void* d_out, int out_size, void* d_ws, size_t ws_size,
                              hipStream_t stream) {
  const float* x  = (const float*)d_in[0];
  const float* qw = (const float*)d_in[2];
  const float* kw = (const float*)d_in[8];
  const float* vw = (const float*)d_in[14];
  const float* pw = (const float*)d_in[20];

  char* ws = (char*)d_ws;
  unsigned short* X2   = (unsigned short*)(ws + 0);            // 32 MB [16384][1024]
  unsigned short* Wqk3 = (unsigned short*)(ws + 33554432ull);  // 3 MB  [1024][1536]
  unsigned short* Wvb  = (unsigned short*)(ws + 36700160ull);  // 0.5 MB
  float*          yqk  = (float*)(ws + 50331648ull);           // 64 MB [16384][1024]
  unsigned short* yv   = (unsigned short*)(ws + 117440512ull); // 16 MB
  unsigned short* Wpb  = (unsigned short*)(ws + 134217728ull); // 0.5 MB (live to end)
  float*          scl  = (float*)(ws + 134742016ull);          // 8 KB [2048]
  float*          sft  = (float*)(ws + 134750208ull);          // 8 KB
  // after QKV gemm (X2/W dead):
  unsigned short* qsb = (unsigned short*)(ws + 0);             // 16 MB
  unsigned short* ktb = (unsigned short*)(ws + 16777216ull);   // 16 MB
  unsigned short* vtb = (unsigned short*)(ws + 33554432ull);   // 16 MB
  // after lif (yqk dead):
  float*          kvp = (float*)(ws + 50331648ull);            // 16 MB
  unsigned short* kvt = (unsigned short*)(ws + 67108864ull);   // 1 MB
  unsigned short* ob  = (unsigned short*)(ws + 68157440ull);   // 16 MB

  prep_split_x<<<dim3(M_ * C_ / 4 / 256), 256, 0, stream>>>(x, X2, M_ * C_);
  prep_weights<<<dim3(C_ * C_ / 4 / 256, 1, 4), 256, 0, stream>>>(qw, kw, vw, pw, Wqk3, Wvb, Wpb);

  BnParams bp;
  bp.p[0]=(const float*)d_in[3];  bp.p[1]=(const float*)d_in[4];  bp.p[2]=(const float*)d_in[5];  bp.p[3]=(const float*)d_in[6];  bp.p[4]=(const float*)d_in[7];
  bp.p[5]=(const float*)d_in[9];  bp.p[6]=(const float*)d_in[10]; bp.p[7]=(const float*)d_in[11]; bp.p[8]=(const float*)d_in[12]; bp.p[9]=(const float*)d_in[13];
  bp.p[10]=(const float*)d_in[15];bp.p[11]=(const float*)d_in[16];bp.p[12]=(const float*)d_in[17];bp.p[13]=(const float*)d_in[18];bp.p[14]=(const float*)d_in[19];
  bp.p[15]=(const float*)d_in[21];bp.p[16]=(const float*)d_in[22];bp.p[17]=(const float*)d_in[23];bp.p[18]=(const float*)d_in[24];bp.p[19]=(const float*)d_in[25];
  bn_prep<<<dim3(8), 256, 0, stream>>>(bp, scl, sft);

  Job2 jqk{X2, 1024, Wqk3, 1536, 1536, 1024, scl, sft, yqk, nullptr};
  gemm_bn<<<dim3(256), 512, 0, stream>>>(jqk, 2);   // 64 panels x 4 n-tiles, 1/CU
  Job2 jv {X2, 1024, Wvb,  512,  512,  512,  scl + 1024, sft + 1024, nullptr, yv};
  gemm_bn<<<dim3(128), 512, 0, stream>>>(jv, 1);    // 64 panels x 2 n-tiles

  lif_transpose<<<dim3(C_ / 64, N_ / 64, B_), 256, 0, stream>>>(yqk, yv, qsb, ktb, vtb);

  kv_gemm<<<dim3(256), 256, 0, stream>>>(ktb, vtb, kvp);
  kv_reduce<<<dim3(512), 256, 0, stream>>>(kvp, kvt);
  av_gemm<<<dim3(128), 256, 0, stream>>>(qsb, kvt, ob);

  Job2 jp{ob, 512, Wpb, 512, 512, 512, scl + 1536, sft + 1536, (float*)d_out, nullptr};
  gemm_bn<<<dim3(128), 512, 0, stream>>>(jp, 1);
}

// Round 6
// 160.136 us; speedup vs baseline: 1.2766x; 1.0677x over previous
//
#include <hip/hip_runtime.h>

// SSA forward, f32 I/O:
//   q = heads(lif(bn(x Wq^T))), k = heads(lif(bn(x Wk^T))), v = heads(bn(x Wv^T))
//   o = 0.125 * q @ (k^T v)   (no softmax -> associativity), out = bn(o Wp^T)
// Q/K GEMMs use 3-term bf16 split (xh*wh + xl*wh + xh*wl) for ~f32 accuracy.
// ROW PERMUTATION m' = ((b*N+n)*T + t): the 4 timesteps of one (b,n,c) land in
// one lane's 4 acc registers -> LIF fused into the GEMM epilogue (no f32
// intermediate). GEMM core: 256x256, BK=32, 8 waves, 4 LDS bufs, register-
// pipelined (read->use distance 1 phase), counted vmcnt, XOR swizzle, setprio.

#define T_ 4
#define B_ 4
#define N_ 1024
#define C_ 512
#define H_ 8
#define M_ (T_*B_*N_)   // 16384

typedef __bf16 bf16x8 __attribute__((ext_vector_type(8)));
typedef float  floatx4 __attribute__((ext_vector_type(4)));

__device__ __forceinline__ float bf2f(unsigned short u) {
  union { unsigned int i; float f; } v; v.i = ((unsigned int)u) << 16; return v.f;
}
__device__ __forceinline__ unsigned short f2bf(float f) {
  unsigned int x = __float_as_uint(f);
  return (unsigned short)((x + 0x7fffu + ((x >> 16) & 1u)) >> 16);  // RNE
}

#define GLOAD16(gaddr, ldsbase) \
  __builtin_amdgcn_global_load_lds((__attribute__((address_space(1))) void*)(gaddr), \
                                   (__attribute__((address_space(3))) void*)(ldsbase), 16, 0, 0)

// x [t,b,n,c] f32 -> X2 [m'][1024] bf16 2-seg [hi|lo], m' = ((b*N+n)*T+t)
__global__ __launch_bounds__(256) void prep_split_x(const float* __restrict__ src,
                                                    unsigned short* __restrict__ dst,
                                                    int nelem) {
  const int idx = (blockIdx.x * 256 + threadIdx.x) * 4;
  if (idx >= nelem) return;
  const float4 v = *(const float4*)(src + idx);
  const int m = idx >> 9, k = idx & 511;
  const int t = m >> 12, b = (m >> 10) & 3, n = m & 1023;
  const int mp = (((b << 10) | n) << 2) | t;
  const size_t base = (size_t)mp * 1024 + k;
  float vv[4] = {v.x, v.y, v.z, v.w};
  unsigned short h[4], l[4];
#pragma unroll
  for (int j = 0; j < 4; ++j) { h[j] = f2bf(vv[j]); l[j] = f2bf(vv[j] - bf2f(h[j])); }
  *(ushort4*)(dst + base) = ushort4{h[0], h[1], h[2], h[3]};
  *(ushort4*)(dst + base + 512) = ushort4{l[0], l[1], l[2], l[3]};
}

// weight preps: z=0 qw, z=1 kw -> Wqk3 3-seg [hi|hi|lo] stride 1536; z=2 vw, z=3 pw -> cast
__global__ __launch_bounds__(256) void prep_weights(const float* __restrict__ qw,
                                                    const float* __restrict__ kw,
                                                    const float* __restrict__ vw,
                                                    const float* __restrict__ pw,
                                                    unsigned short* __restrict__ Wqk3,
                                                    unsigned short* __restrict__ Wvb,
                                                    unsigned short* __restrict__ Wpb) {
  const int z = blockIdx.z;
  const int idx = (blockIdx.x * 256 + threadIdx.x) * 4;
  if (idx >= C_ * C_) return;
  const float* src = (z == 0) ? qw : (z == 1) ? kw : (z == 2) ? vw : pw;
  const float4 v = *(const float4*)(src + idx);
  if (z >= 2) {
    unsigned short* dst = (z == 2) ? Wvb : Wpb;
    *(ushort4*)(dst + idx) = ushort4{f2bf(v.x), f2bf(v.y), f2bf(v.z), f2bf(v.w)};
    return;
  }
  const int row = idx >> 9, k = idx & 511;
  unsigned short* dst = Wqk3 + (size_t)(z * 512) * 1536;
  const size_t base = (size_t)row * 1536 + k;
  float vv[4] = {v.x, v.y, v.z, v.w};
  unsigned short h[4], l[4];
#pragma unroll
  for (int j = 0; j < 4; ++j) { h[j] = f2bf(vv[j]); l[j] = f2bf(vv[j] - bf2f(h[j])); }
  ushort4 hi{h[0], h[1], h[2], h[3]};
  *(ushort4*)(dst + base) = hi;
  *(ushort4*)(dst + base + 512) = hi;
  *(ushort4*)(dst + base + 1024) = ushort4{l[0], l[1], l[2], l[3]};
}

struct BnParams { const float* p[20]; };
__global__ __launch_bounds__(256) void bn_prep(BnParams P, float* __restrict__ scl,
                                               float* __restrict__ sft) {
  const int o = blockIdx.x * 256 + threadIdx.x;  // 0..2047
  const int grp = o >> 9, ci = o & 511;
  const float* bias = P.p[grp * 5 + 0];
  const float* g    = P.p[grp * 5 + 1];
  const float* bt   = P.p[grp * 5 + 2];
  const float* mu   = P.p[grp * 5 + 3];
  const float* var  = P.p[grp * 5 + 4];
  const float s = g[ci] * rsqrtf(var[ci] + 1e-5f);
  scl[o] = s;
  sft[o] = (bias[ci] - mu[ci]) * s + bt[ci];
}

struct Job2 {
  const unsigned short* A; int lda;
  const unsigned short* w; int ldb;
  int K, ldc, epi;           // epi: 1=bf16 out, 2=LIF dual bf16 (q|k), 3=f32 unpermuted
  const float* scl; const float* sft;
  float* out32; unsigned short* out16; unsigned short* out16b;
};

// ---------------------------------------------------------------------------
// y[m,n] = sum_k A[m,k] W[n,k] (+ BN/LIF epilogue).  Core identical to r5.
// ---------------------------------------------------------------------------
__global__ __launch_bounds__(512, 2) void gemm_bn(Job2 job, int lntile) {
  const int xcd = blockIdx.x & 7, slot = blockIdx.x >> 3;
  const int ntm1 = (1 << lntile) - 1;
  const int panel = xcd + 8 * (slot >> lntile);
  const int m0 = panel * 256;
  const int n0 = (slot & ntm1) * 256;

  const int tid = threadIdx.x;
  const int wv = tid >> 6, lane = tid & 63;
  const int wm = wv >> 1, wn = wv & 1;          // wave tile 64 rows x 128 cols
  const int NT = job.K >> 5;                    // K-tiles of 32

  __shared__ unsigned short AB[4][256 * 64];

  const int rloc = lane >> 3;
  const int ulog = (lane & 7) ^ rloc;
  const bool isA = ulog < 4;
  const unsigned short* bq[4];
#pragma unroll
  for (int q = 0; q < 4; ++q) {
    const int row = wv * 32 + q * 8 + rloc;
    bq[q] = isA ? job.A + (size_t)(m0 + row) * job.lda + ulog * 8
                : job.w + (size_t)(n0 + row) * job.ldb + (ulog - 4) * 8;
  }

#define ISSUE(T_, BUF_) do {                                                 \
    const int t_ = (T_);                                                     \
    const int off_ = isA ? ((t_ < 32 ? t_ : t_ - 32) << 5) : (t_ << 5);      \
    _Pragma("unroll")                                                        \
    for (int q = 0; q < 4; ++q)                                              \
      GLOAD16(bq[q] + off_, &AB[BUF_][(wv * 32 + q * 8) * 64]);              \
  } while (0)

  const int r15 = lane & 15;
  const int apos = (lane >> 4) ^ (lane & 7);
  const int bpos = (4 | (lane >> 4)) ^ (lane & 7);
  const int aoff = (wm * 64 + r15) * 64 + apos * 8;
  const int boff = (wn * 128 + r15) * 64 + bpos * 8;

  bf16x8 A0[4], A1[4], L0[4], L1[4], Hh[4];

#define RD_ALO(BUF_, AX, LX) do {                                            \
    const unsigned short* lb_ = &AB[BUF_][0];                                \
    _Pragma("unroll")                                                        \
    for (int i_ = 0; i_ < 4; ++i_) AX[i_] = *(const bf16x8*)(lb_ + aoff + i_ * 1024); \
    _Pragma("unroll")                                                        \
    for (int j_ = 0; j_ < 4; ++j_) LX[j_] = *(const bf16x8*)(lb_ + boff + j_ * 1024); \
  } while (0)

#define RD_HI(BUF_) do {                                                     \
    const unsigned short* lb_ = &AB[BUF_][0];                                \
    _Pragma("unroll")                                                        \
    for (int j_ = 0; j_ < 4; ++j_) Hh[j_] = *(const bf16x8*)(lb_ + boff + (4 + j_) * 1024); \
  } while (0)

#define MF_LO(AX, LX) do {                                                   \
    __builtin_amdgcn_s_setprio(1);                                           \
    _Pragma("unroll")                                                        \
    for (int i_ = 0; i_ < 4; ++i_)                                           \
    _Pragma("unroll")                                                        \
      for (int j_ = 0; j_ < 4; ++j_)                                         \
        acc[i_][j_] = __builtin_amdgcn_mfma_f32_16x16x32_bf16(AX[i_], LX[j_], acc[i_][j_], 0, 0, 0); \
    __builtin_amdgcn_s_setprio(0);                                           \
  } while (0)

#define MF_HI(AX) do {                                                       \
    __builtin_amdgcn_s_setprio(1);                                           \
    _Pragma("unroll")                                                        \
    for (int i_ = 0; i_ < 4; ++i_)                                           \
    _Pragma("unroll")                                                        \
      for (int j_ = 0; j_ < 4; ++j_)                                         \
        acc[i_][4 + j_] = __builtin_amdgcn_mfma_f32_16x16x32_bf16(AX[i_], Hh[j_], acc[i_][4 + j_], 0, 0, 0); \
    __builtin_amdgcn_s_setprio(0);                                           \
  } while (0)

#define MIDBAR(N_) do {                                                      \
    asm volatile("s_waitcnt vmcnt(" #N_ ")" ::: "memory");                   \
    __builtin_amdgcn_s_barrier();                                            \
    __builtin_amdgcn_sched_barrier(0);                                       \
  } while (0)

#define SLOT_I(KT_, BC_, BN_, AX, LX, AY, LY) do {                           \
    RD_HI(BC_); MF_LO(AX, LX);                                               \
    MIDBAR(4);                                                               \
    ISSUE((KT_) + 3, (BC_ + 3) & 3);                                         \
    RD_ALO(BN_, AY, LY); MF_HI(AX);                                          \
  } while (0)

  floatx4 acc[4][8];
#pragma unroll
  for (int i = 0; i < 4; ++i)
#pragma unroll
    for (int j = 0; j < 8; ++j) acc[i][j] = floatx4{0.f, 0.f, 0.f, 0.f};

  ISSUE(0, 0); ISSUE(1, 1); ISSUE(2, 2);
  asm volatile("s_waitcnt vmcnt(4)" ::: "memory");
  __builtin_amdgcn_s_barrier();
  __builtin_amdgcn_sched_barrier(0);
  RD_ALO(0, A0, L0);

  const int NG = (NT - 4) >> 2;
  for (int g = 0; g < NG; ++g) {
    const int g4 = g << 2;
    SLOT_I(g4 + 0, 0, 1, A0, L0, A1, L1);
    SLOT_I(g4 + 1, 1, 2, A1, L1, A0, L0);
    SLOT_I(g4 + 2, 2, 3, A0, L0, A1, L1);
    SLOT_I(g4 + 3, 3, 0, A1, L1, A0, L0);
  }
  SLOT_I(NT - 4, 0, 1, A0, L0, A1, L1);
  RD_HI(1); MF_LO(A1, L1); MIDBAR(4); RD_ALO(2, A0, L0); MF_HI(A1);
  RD_HI(2); MF_LO(A0, L0); MIDBAR(0); RD_ALO(3, A1, L1); MF_HI(A0);
  RD_HI(3); MF_LO(A1, L1); MF_HI(A1);

  // ---- epilogue
  float scl[8], sft[8];
#pragma unroll
  for (int j = 0; j < 8; ++j) {
    const int c = n0 + wn * 128 + j * 16 + r15;
    scl[j] = job.scl[c];
    sft[j] = job.sft[c];
  }
  const int rbase = m0 + wm * 64 + (lane >> 4) * 4;

  if (job.epi == 2) {
    // BN -> in-register LIF over r (=t), spikes to qs (cols<512) or ks
    const bool isQ = (n0 < 512);
    unsigned short* outp = isQ ? job.out16 : job.out16b;
    const int cb = n0 + wn * 128 + r15 - (isQ ? 0 : 512);
#pragma unroll
    for (int i = 0; i < 4; ++i) {
      unsigned short spk[4][8];
#pragma unroll
      for (int j = 0; j < 8; ++j) {
        float vme = 0.f;
#pragma unroll
        for (int r = 0; r < 4; ++r) {
          const float y = acc[i][j][r] * scl[j] + sft[j];
          vme += (y - vme) * 0.5f;
          const bool sp = vme >= 1.0f;
          spk[r][j] = sp ? (unsigned short)0x3F80 : (unsigned short)0;
          if (sp) vme = 0.f;
        }
      }
#pragma unroll
      for (int r = 0; r < 4; ++r) {
        unsigned short* prow = outp + (size_t)(rbase + 16 * i + r) * 512 + cb;
#pragma unroll
        for (int j = 0; j < 8; ++j) prow[j * 16] = spk[r][j];
      }
    }
  } else if (job.epi == 3) {
    // f32 out with m' -> standard row un-permutation
#pragma unroll
    for (int i = 0; i < 4; ++i)
#pragma unroll
      for (int r = 0; r < 4; ++r) {
        const int mp = rbase + 16 * i + r;
        const int t = mp & 3, bn = mp >> 2;
        const int mstd = (((t << 2) | (bn >> 10)) << 10) | (bn & 1023);
        float* prow = job.out32 + (size_t)mstd * 512 + n0 + wn * 128 + r15;
#pragma unroll
        for (int j = 0; j < 8; ++j) prow[j * 16] = acc[i][j][r] * scl[j] + sft[j];
      }
  } else {
#pragma unroll
    for (int i = 0; i < 4; ++i)
#pragma unroll
      for (int r = 0; r < 4; ++r) {
        unsigned short* prow = job.out16 + (size_t)(rbase + 16 * i + r) * job.ldc + n0 + wn * 128 + r15;
#pragma unroll
        for (int j = 0; j < 8; ++j) prow[j * 16] = f2bf(acc[i][j][r] * scl[j] + sft[j]);
      }
  }
}

// ---------------------------------------------------------------------------
// ks,vs [m'][512] -> ktr,vtr [((t*4+b)*512+c)][1024 n]
// ---------------------------------------------------------------------------
__global__ __launch_bounds__(256) void transpose_kv(
    const unsigned short* __restrict__ ks, const unsigned short* __restrict__ vs,
    unsigned short* __restrict__ ktr, unsigned short* __restrict__ vtr) {
  const int c0 = blockIdx.x * 64;   // 8
  const int n0 = blockIdx.y * 64;   // 16
  const int b  = blockIdx.z;        // 4
  const int tid = threadIdx.x;
  const int rr = tid >> 2;          // load: n row 0..63
  const int cc = (tid & 3) * 16;    // load: 16-short c chunk
  const int nn = tid & 31;          // store: u32 col (2 n)
  __shared__ unsigned short tile[64][65];

  for (int which = 0; which < 2; ++which) {
    const unsigned short* src = which ? vs : ks;
    unsigned short* dst = which ? vtr : ktr;
    for (int t = 0; t < 4; ++t) {
      const size_t srow = (size_t)((((b << 10) | (n0 + rr)) << 2) | t) * 512 + c0 + cc;
      const uint4 d0 = *(const uint4*)(src + srow);
      const uint4 d1 = *(const uint4*)(src + srow + 8);
      __syncthreads();
      const unsigned int w[8] = {d0.x, d0.y, d0.z, d0.w, d1.x, d1.y, d1.z, d1.w};
#pragma unroll
      for (int e = 0; e < 8; ++e) {
        tile[rr][cc + 2 * e]     = (unsigned short)(w[e] & 0xffffu);
        tile[rr][cc + 2 * e + 1] = (unsigned short)(w[e] >> 16);
      }
      __syncthreads();
      const size_t drowbase = ((size_t)(((t << 2) | b) * 512 + c0)) * 1024 + n0;
#pragma unroll
      for (int g = 0; g < 8; ++g) {
        const int c = (tid >> 5) + 8 * g;
        const unsigned int lo = tile[2 * nn][c];
        const unsigned int hi = tile[2 * nn + 1][c];
        *(unsigned int*)(dst + drowbase + (size_t)c * 1024 + 2 * nn) = lo | (hi << 16);
      }
    }
  }
}

// ---------------------------------------------------------------------------
__global__ __launch_bounds__(256) void kv_gemm(const unsigned short* __restrict__ ktr,
                                               const unsigned short* __restrict__ vtr,
                                               float* __restrict__ kvp) {
  const int bid = blockIdx.x;
  const int head = bid >> 1;
  const int mh = bid & 1;
  const int tb = head >> 3;
  const int h = head & 7;
  const int wv = threadIdx.x >> 6, lane = threadIdx.x & 63;
  const int m0 = mh * 512 + wv * 128;
  const size_t cbase = (size_t)tb * C_ + h * 64;
  const int rsel = lane & 15, koff = (lane >> 4) * 8;

  floatx4 acc[4][4];
#pragma unroll
  for (int i = 0; i < 4; ++i)
#pragma unroll
    for (int j = 0; j < 4; ++j) acc[i][j] = floatx4{0.f, 0.f, 0.f, 0.f};

#pragma unroll
  for (int s = 0; s < 4; ++s) {
    const int m = m0 + s * 32 + koff;
    bf16x8 a[4], b[4];
#pragma unroll
    for (int dt = 0; dt < 4; ++dt)
      a[dt] = *(const bf16x8*)(ktr + (cbase + dt * 16 + rsel) * N_ + m);
#pragma unroll
    for (int et = 0; et < 4; ++et)
      b[et] = *(const bf16x8*)(vtr + (cbase + et * 16 + rsel) * N_ + m);
#pragma unroll
    for (int dt = 0; dt < 4; ++dt)
#pragma unroll
      for (int et = 0; et < 4; ++et)
        acc[dt][et] = __builtin_amdgcn_mfma_f32_16x16x32_bf16(a[dt], b[et], acc[dt][et], 0, 0, 0);
  }

  float* outp = kvp + ((size_t)head * 8 + mh * 4 + wv) * 4096;
  const int dbase = (lane >> 4) * 4;
  const int e0 = lane & 15;
#pragma unroll
  for (int dt = 0; dt < 4; ++dt)
#pragma unroll
    for (int et = 0; et < 4; ++et)
#pragma unroll
      for (int r = 0; r < 4; ++r)
        outp[(dt * 16 + dbase + r) * 64 + et * 16 + e0] = acc[dt][et][r];
}

__global__ __launch_bounds__(256) void kv_reduce(const float* __restrict__ kvp,
                                                 unsigned short* __restrict__ kvt) {
  const int gid = blockIdx.x * 256 + threadIdx.x;
  const int idx4 = gid * 4;
  const int head = idx4 >> 12;
  const int rem = idx4 & 4095;
  const int e = rem >> 6, d0 = rem & 63;
  const float* p = kvp + (size_t)head * 8 * 4096;
  unsigned short rr[4];
#pragma unroll
  for (int j = 0; j < 4; ++j) {
    float s = 0.f;
#pragma unroll
    for (int pp = 0; pp < 8; ++pp) s += p[pp * 4096 + (d0 + j) * 64 + e];
    rr[j] = f2bf(0.125f * s);
  }
  uint2 o;
  o.x = (unsigned)rr[0] | ((unsigned)rr[1] << 16);
  o.y = (unsigned)rr[2] | ((unsigned)rr[3] << 16);
  *(uint2*)(kvt + idx4) = o;
}

// O rows in m' layout: row(n;t,b) = ((b<<10|n)<<2)|t
__global__ __launch_bounds__(256) void av_gemm(const unsigned short* __restrict__ qs,
                                               const unsigned short* __restrict__ kvt,
                                               unsigned short* __restrict__ obuf) {
  const int bx = blockIdx.x;
  const int tb = bx >> 3, nt = bx & 7;
  const int t = tb >> 2, b = tb & 3;
  const int wv = threadIdx.x >> 6, lane = threadIdx.x & 63;
  const int n0 = nt * 128 + wv * 32;
  const int rsel = lane & 15, koff = (lane >> 4) * 8;

#pragma unroll 1
  for (int h = 0; h < H_; ++h) {
    floatx4 acc[2][4];
#pragma unroll
    for (int i = 0; i < 2; ++i)
#pragma unroll
      for (int j = 0; j < 4; ++j) acc[i][j] = floatx4{0.f, 0.f, 0.f, 0.f};
    const unsigned short* kvh = kvt + ((size_t)tb * 8 + h) * 4096;
#pragma unroll
    for (int s = 0; s < 2; ++s) {
      bf16x8 a[2], bv[4];
#pragma unroll
      for (int i = 0; i < 2; ++i) {
        const int n = n0 + i * 16 + rsel;
        a[i] = *(const bf16x8*)(qs + (size_t)((((b << 10) | n) << 2) | t) * 512 + h * 64 + s * 32 + koff);
      }
#pragma unroll
      for (int et = 0; et < 4; ++et)
        bv[et] = *(const bf16x8*)(kvh + (et * 16 + rsel) * 64 + s * 32 + koff);
#pragma unroll
      for (int i = 0; i < 2; ++i)
#pragma unroll
        for (int et = 0; et < 4; ++et)
          acc[i][et] = __builtin_amdgcn_mfma_f32_16x16x32_bf16(a[i], bv[et], acc[i][et], 0, 0, 0);
    }
#pragma unroll
    for (int i = 0; i < 2; ++i)
#pragma unroll
      for (int et = 0; et < 4; ++et)
#pragma unroll
        for (int r = 0; r < 4; ++r) {
          const int n = n0 + i * 16 + (lane >> 4) * 4 + r;
          obuf[(size_t)((((b << 10) | n) << 2) | t) * 512 + h * 64 + et * 16 + rsel] = f2bf(acc[i][et][r]);
        }
  }
}

// ---------------------------------------------------------------------------
extern "C" void kernel_launch(void* const* d_in, const int* in_sizes, int n_in,
                              void* d_out, int out_size, void* d_ws, size_t ws_size,
                              hipStream_t stream) {
  const float* x  = (const float*)d_in[0];
  const float* qw = (const float*)d_in[2];
  const float* kw = (const float*)d_in[8];
  const float* vw = (const float*)d_in[14];
  const float* pw = (const float*)d_in[20];

  char* ws = (char*)d_ws;
  unsigned short* X2   = (unsigned short*)(ws + 0);            // 32 MB [16384][1024] (m' rows)
  unsigned short* Wqk3 = (unsigned short*)(ws + 33554432ull);  // 3 MB  [1024][1536]
  unsigned short* Wvb  = (unsigned short*)(ws + 36700160ull);  // 0.5 MB
  unsigned short* Wpb  = (unsigned short*)(ws + 37224448ull);  // 0.5 MB
  float*          scl  = (float*)(ws + 37748736ull);           // 8 KB [2048]
  float*          sft  = (float*)(ws + 37756928ull);           // 8 KB
  unsigned short* qsb  = (unsigned short*)(ws + 50331648ull);  // 16 MB [m'][512] spikes
  unsigned short* ksb  = (unsigned short*)(ws + 67108864ull);  // 16 MB
  unsigned short* vsb  = (unsigned short*)(ws + 83886080ull);  // 16 MB
  // after gemms, X2 dead:
  unsigned short* ktb  = (unsigned short*)(ws + 0);            // 16 MB [t,b,c,n]
  unsigned short* vtb  = (unsigned short*)(ws + 16777216ull);  // 16 MB
  float*          kvp  = (float*)(ws + 100663296ull);          // 16 MB
  unsigned short* kvt  = (unsigned short*)(ws + 117440512ull); // 1 MB
  unsigned short* ob   = (unsigned short*)(ws + 118489088ull); // 16 MB [m'][512]

  prep_split_x<<<dim3(M_ * C_ / 4 / 256), 256, 0, stream>>>(x, X2, M_ * C_);
  prep_weights<<<dim3(C_ * C_ / 4 / 256, 1, 4), 256, 0, stream>>>(qw, kw, vw, pw, Wqk3, Wvb, Wpb);

  BnParams bp;
  bp.p[0]=(const float*)d_in[3];  bp.p[1]=(const float*)d_in[4];  bp.p[2]=(const float*)d_in[5];  bp.p[3]=(const float*)d_in[6];  bp.p[4]=(const float*)d_in[7];
  bp.p[5]=(const float*)d_in[9];  bp.p[6]=(const float*)d_in[10]; bp.p[7]=(const float*)d_in[11]; bp.p[8]=(const float*)d_in[12]; bp.p[9]=(const float*)d_in[13];
  bp.p[10]=(const float*)d_in[15];bp.p[11]=(const float*)d_in[16];bp.p[12]=(const float*)d_in[17];bp.p[13]=(const float*)d_in[18];bp.p[14]=(const float*)d_in[19];
  bp.p[15]=(const float*)d_in[21];bp.p[16]=(const float*)d_in[22];bp.p[17]=(const float*)d_in[23];bp.p[18]=(const float*)d_in[24];bp.p[19]=(const float*)d_in[25];
  bn_prep<<<dim3(8), 256, 0, stream>>>(bp, scl, sft);

  Job2 jqk{X2, 1024, Wqk3, 1536, 1536, 512, 2, scl, sft, nullptr, qsb, ksb};
  gemm_bn<<<dim3(256), 512, 0, stream>>>(jqk, 2);   // 64 panels x 4 n-tiles
  Job2 jv {X2, 1024, Wvb,  512,  512,  512, 1, scl + 1024, sft + 1024, nullptr, vsb, nullptr};
  gemm_bn<<<dim3(128), 512, 0, stream>>>(jv, 1);    // 64 panels x 2 n-tiles

  transpose_kv<<<dim3(8, 16, 4), 256, 0, stream>>>(ksb, vsb, ktb, vtb);

  kv_gemm<<<dim3(256), 256, 0, stream>>>(ktb, vtb, kvp);
  kv_reduce<<<dim3(512), 256, 0, stream>>>(kvp, kvt);
  av_gemm<<<dim3(128), 256, 0, stream>>>(qsb, kvt, ob);

  Job2 jp{ob, 512, Wpb, 512, 512, 512, 3, scl + 1536, sft + 1536, (float*)d_out, nullptr, nullptr};
  gemm_bn<<<dim3(128), 512, 0, stream>>>(jp, 1);
}

// Round 7
// 141.067 us; speedup vs baseline: 1.4492x; 1.1352x over previous
//
#include <hip/hip_runtime.h>

// SSA forward, f32 I/O:
//   q = heads(lif(bn(x Wq^T))), k = heads(lif(bn(x Wk^T))), v = heads(bn(x Wv^T))
//   o = 0.125 * q @ (k^T v)   (no softmax -> associativity), out = bn(o Wp^T)
// Q/K GEMMs: 3-term bf16 split (xh*wh + xl*wh + xh*wl) for ~f32 accuracy.
// Row permutation m' = ((b*N+n)*T + t): 4 timesteps land in one lane's 4 acc
// regs -> LIF fused in epilogue. k/v outputs written DIRECTLY transposed
// [t,b,c,n] via LDS-transpose epilogue (no separate transpose kernel).
// GEMM cores register-pipelined: read->use distance 1 slot, counted vmcnt,
// XOR-swizzled LDS both sides, setprio. 256x256 (qk) + 128x256 (v/proj).

#define T_ 4
#define B_ 4
#define N_ 1024
#define C_ 512
#define H_ 8
#define M_ (T_*B_*N_)   // 16384

typedef __bf16 bf16x8 __attribute__((ext_vector_type(8)));
typedef float  floatx4 __attribute__((ext_vector_type(4)));

__device__ __forceinline__ float bf2f(unsigned short u) {
  union { unsigned int i; float f; } v; v.i = ((unsigned int)u) << 16; return v.f;
}
__device__ __forceinline__ unsigned short f2bf(float f) {
  unsigned int x = __float_as_uint(f);
  return (unsigned short)((x + 0x7fffu + ((x >> 16) & 1u)) >> 16);  // RNE
}

#define GLOAD16(gaddr, ldsbase) \
  __builtin_amdgcn_global_load_lds((__attribute__((address_space(1))) void*)(gaddr), \
                                   (__attribute__((address_space(3))) void*)(ldsbase), 16, 0, 0)

// x [t,b,n,c] f32 -> X2 [m'][1024] bf16 2-seg [hi|lo], m' = ((b*N+n)*T+t)
__global__ __launch_bounds__(256) void prep_split_x(const float* __restrict__ src,
                                                    unsigned short* __restrict__ dst,
                                                    int nelem) {
  const int idx = (blockIdx.x * 256 + threadIdx.x) * 4;
  if (idx >= nelem) return;
  const float4 v = *(const float4*)(src + idx);
  const int m = idx >> 9, k = idx & 511;
  const int t = m >> 12, b = (m >> 10) & 3, n = m & 1023;
  const int mp = (((b << 10) | n) << 2) | t;
  const size_t base = (size_t)mp * 1024 + k;
  float vv[4] = {v.x, v.y, v.z, v.w};
  unsigned short h[4], l[4];
#pragma unroll
  for (int j = 0; j < 4; ++j) { h[j] = f2bf(vv[j]); l[j] = f2bf(vv[j] - bf2f(h[j])); }
  *(ushort4*)(dst + base) = ushort4{h[0], h[1], h[2], h[3]};
  *(ushort4*)(dst + base + 512) = ushort4{l[0], l[1], l[2], l[3]};
}

// weight preps: z=0 qw, z=1 kw -> Wqk3 3-seg [hi|hi|lo] stride 1536; z=2 vw, z=3 pw -> cast
__global__ __launch_bounds__(256) void prep_weights(const float* __restrict__ qw,
                                                    const float* __restrict__ kw,
                                                    const float* __restrict__ vw,
                                                    const float* __restrict__ pw,
                                                    unsigned short* __restrict__ Wqk3,
                                                    unsigned short* __restrict__ Wvb,
                                                    unsigned short* __restrict__ Wpb) {
  const int z = blockIdx.z;
  const int idx = (blockIdx.x * 256 + threadIdx.x) * 4;
  if (idx >= C_ * C_) return;
  const float* src = (z == 0) ? qw : (z == 1) ? kw : (z == 2) ? vw : pw;
  const float4 v = *(const float4*)(src + idx);
  if (z >= 2) {
    unsigned short* dst = (z == 2) ? Wvb : Wpb;
    *(ushort4*)(dst + idx) = ushort4{f2bf(v.x), f2bf(v.y), f2bf(v.z), f2bf(v.w)};
    return;
  }
  const int row = idx >> 9, k = idx & 511;
  unsigned short* dst = Wqk3 + (size_t)(z * 512) * 1536;
  const size_t base = (size_t)row * 1536 + k;
  float vv[4] = {v.x, v.y, v.z, v.w};
  unsigned short h[4], l[4];
#pragma unroll
  for (int j = 0; j < 4; ++j) { h[j] = f2bf(vv[j]); l[j] = f2bf(vv[j] - bf2f(h[j])); }
  ushort4 hi{h[0], h[1], h[2], h[3]};
  *(ushort4*)(dst + base) = hi;
  *(ushort4*)(dst + base + 512) = hi;
  *(ushort4*)(dst + base + 1024) = ushort4{l[0], l[1], l[2], l[3]};
}

struct BnParams { const float* p[20]; };
__global__ __launch_bounds__(256) void bn_prep(BnParams P, float* __restrict__ scl,
                                               float* __restrict__ sft) {
  const int o = blockIdx.x * 256 + threadIdx.x;  // 0..2047
  const int grp = o >> 9, ci = o & 511;
  const float* bias = P.p[grp * 5 + 0];
  const float* g    = P.p[grp * 5 + 1];
  const float* bt   = P.p[grp * 5 + 2];
  const float* mu   = P.p[grp * 5 + 3];
  const float* var  = P.p[grp * 5 + 4];
  const float s = g[ci] * rsqrtf(var[ci] + 1e-5f);
  scl[o] = s;
  sft[o] = (bias[ci] - mu[ci]) * s + bt[ci];
}

struct Job2 {
  const unsigned short* A; int lda;
  const unsigned short* w; int ldb;
  int K, ldc, epi;  // epi: 2=qk dual (q->qsb, k->LDS-transpose->ktr)
                    //      3=f32 unpermuted, 4=bf16 LDS-transpose (v->vtr)
  const float* scl; const float* sft;
  float* out32; unsigned short* out16; unsigned short* out16b;
};

// ---------------------------------------------------------------------------
// 256x256 GEMM (qk): y[m,n] = sum_k A[m,k] W[n,k]. Core frozen from r5/r6.
// ---------------------------------------------------------------------------
__global__ __launch_bounds__(512, 2) void gemm_bn(Job2 job, int lntile) {
  const int xcd = blockIdx.x & 7, slot = blockIdx.x >> 3;
  const int ntm1 = (1 << lntile) - 1;
  const int panel = xcd + 8 * (slot >> lntile);
  const int m0 = panel * 256;
  const int n0 = (slot & ntm1) * 256;

  const int tid = threadIdx.x;
  const int wv = tid >> 6, lane = tid & 63;
  const int wm = wv >> 1, wn = wv & 1;          // wave tile 64 rows x 128 cols
  const int NT = job.K >> 5;

  __shared__ unsigned short AB[4][256 * 64];

  const int rloc = lane >> 3;
  const int ulog = (lane & 7) ^ rloc;
  const bool isA = ulog < 4;
  const unsigned short* bq[4];
#pragma unroll
  for (int q = 0; q < 4; ++q) {
    const int row = wv * 32 + q * 8 + rloc;
    bq[q] = isA ? job.A + (size_t)(m0 + row) * job.lda + ulog * 8
                : job.w + (size_t)(n0 + row) * job.ldb + (ulog - 4) * 8;
  }

#define ISSUE(T_, BUF_) do {                                                 \
    const int t_ = (T_);                                                     \
    const int off_ = isA ? ((t_ < 32 ? t_ : t_ - 32) << 5) : (t_ << 5);      \
    _Pragma("unroll")                                                        \
    for (int q = 0; q < 4; ++q)                                              \
      GLOAD16(bq[q] + off_, &AB[BUF_][(wv * 32 + q * 8) * 64]);              \
  } while (0)

  const int r15 = lane & 15;
  const int apos = (lane >> 4) ^ (lane & 7);
  const int bpos = (4 | (lane >> 4)) ^ (lane & 7);
  const int aoff = (wm * 64 + r15) * 64 + apos * 8;
  const int boff = (wn * 128 + r15) * 64 + bpos * 8;

  bf16x8 A0[4], A1[4], L0[4], L1[4], Hh[4];

#define RD_ALO(BUF_, AX, LX) do {                                            \
    const unsigned short* lb_ = &AB[BUF_][0];                                \
    _Pragma("unroll")                                                        \
    for (int i_ = 0; i_ < 4; ++i_) AX[i_] = *(const bf16x8*)(lb_ + aoff + i_ * 1024); \
    _Pragma("unroll")                                                        \
    for (int j_ = 0; j_ < 4; ++j_) LX[j_] = *(const bf16x8*)(lb_ + boff + j_ * 1024); \
  } while (0)

#define RD_HI(BUF_) do {                                                     \
    const unsigned short* lb_ = &AB[BUF_][0];                                \
    _Pragma("unroll")                                                        \
    for (int j_ = 0; j_ < 4; ++j_) Hh[j_] = *(const bf16x8*)(lb_ + boff + (4 + j_) * 1024); \
  } while (0)

#define MF_LO(AX, LX) do {                                                   \
    __builtin_amdgcn_s_setprio(1);                                           \
    _Pragma("unroll")                                                        \
    for (int i_ = 0; i_ < 4; ++i_)                                           \
    _Pragma("unroll")                                                        \
      for (int j_ = 0; j_ < 4; ++j_)                                         \
        acc[i_][j_] = __builtin_amdgcn_mfma_f32_16x16x32_bf16(AX[i_], LX[j_], acc[i_][j_], 0, 0, 0); \
    __builtin_amdgcn_s_setprio(0);                                           \
  } while (0)

#define MF_HI(AX) do {                                                       \
    __builtin_amdgcn_s_setprio(1);                                           \
    _Pragma("unroll")                                                        \
    for (int i_ = 0; i_ < 4; ++i_)                                           \
    _Pragma("unroll")                                                        \
      for (int j_ = 0; j_ < 4; ++j_)                                         \
        acc[i_][4 + j_] = __builtin_amdgcn_mfma_f32_16x16x32_bf16(AX[i_], Hh[j_], acc[i_][4 + j_], 0, 0, 0); \
    __builtin_amdgcn_s_setprio(0);                                           \
  } while (0)

#define MIDBAR(N_) do {                                                      \
    asm volatile("s_waitcnt vmcnt(" #N_ ")" ::: "memory");                   \
    __builtin_amdgcn_s_barrier();                                            \
    __builtin_amdgcn_sched_barrier(0);                                       \
  } while (0)

#define SLOT_I(KT_, BC_, BN_, AX, LX, AY, LY) do {                           \
    RD_HI(BC_); MF_LO(AX, LX);                                               \
    MIDBAR(4);                                                               \
    ISSUE((KT_) + 3, (BC_ + 3) & 3);                                         \
    RD_ALO(BN_, AY, LY); MF_HI(AX);                                          \
  } while (0)

  floatx4 acc[4][8];
#pragma unroll
  for (int i = 0; i < 4; ++i)
#pragma unroll
    for (int j = 0; j < 8; ++j) acc[i][j] = floatx4{0.f, 0.f, 0.f, 0.f};

  ISSUE(0, 0); ISSUE(1, 1); ISSUE(2, 2);
  asm volatile("s_waitcnt vmcnt(4)" ::: "memory");
  __builtin_amdgcn_s_barrier();
  __builtin_amdgcn_sched_barrier(0);
  RD_ALO(0, A0, L0);

  const int NG = (NT - 4) >> 2;
  for (int g = 0; g < NG; ++g) {
    const int g4 = g << 2;
    SLOT_I(g4 + 0, 0, 1, A0, L0, A1, L1);
    SLOT_I(g4 + 1, 1, 2, A1, L1, A0, L0);
    SLOT_I(g4 + 2, 2, 3, A0, L0, A1, L1);
    SLOT_I(g4 + 3, 3, 0, A1, L1, A0, L0);
  }
  SLOT_I(NT - 4, 0, 1, A0, L0, A1, L1);
  RD_HI(1); MF_LO(A1, L1); MIDBAR(4); RD_ALO(2, A0, L0); MF_HI(A1);
  RD_HI(2); MF_LO(A0, L0); MIDBAR(0); RD_ALO(3, A1, L1); MF_HI(A0);
  RD_HI(3); MF_LO(A1, L1); MF_HI(A1);

  // ---- epilogue
  float scl[8], sft[8];
#pragma unroll
  for (int j = 0; j < 8; ++j) {
    const int c = n0 + wn * 128 + j * 16 + r15;
    scl[j] = job.scl[c];
    sft[j] = job.sft[c];
  }
  const int rbase = m0 + wm * 64 + (lane >> 4) * 4;

  if (job.epi == 2 && n0 < 512) {
    // q half: BN -> in-register LIF -> qsb [m'][512]
    const int cb = n0 + wn * 128 + r15;
#pragma unroll
    for (int i = 0; i < 4; ++i) {
      unsigned short spk[4][8];
#pragma unroll
      for (int j = 0; j < 8; ++j) {
        float vme = 0.f;
#pragma unroll
        for (int r = 0; r < 4; ++r) {
          const float y = acc[i][j][r] * scl[j] + sft[j];
          vme += (y - vme) * 0.5f;
          const bool sp = vme >= 1.0f;
          spk[r][j] = sp ? (unsigned short)0x3F80 : (unsigned short)0;
          if (sp) vme = 0.f;
        }
      }
#pragma unroll
      for (int r = 0; r < 4; ++r) {
        unsigned short* prow = job.out16 + (size_t)(rbase + 16 * i + r) * 512 + cb;
#pragma unroll
        for (int j = 0; j < 8; ++j) prow[j * 16] = spk[r][j];
      }
    }
  } else if (job.epi == 2) {
    // k half: BN -> LIF -> LDS [4t][256c][64n] (swizzled) -> ktr [t,b,c,n]
    __syncthreads();
    unsigned short* lds = &AB[0][0];
    const int gq = lane >> 4;
#pragma unroll
    for (int i = 0; i < 4; ++i) {
      const int n_loc = wm * 16 + 4 * i + gq;           // 0..63
#pragma unroll
      for (int j = 0; j < 8; ++j) {
        const int c_loc = wn * 128 + j * 16 + r15;      // 0..255
        const int colbase = c_loc * 64 + (n_loc ^ ((c_loc & 7) << 3));
        float vme = 0.f;
#pragma unroll
        for (int r = 0; r < 4; ++r) {
          const float y = acc[i][j][r] * scl[j] + sft[j];
          vme += (y - vme) * 0.5f;
          const bool sp = vme >= 1.0f;
          lds[r * 16384 + colbase] = sp ? (unsigned short)0x3F80 : (unsigned short)0;
          if (sp) vme = 0.f;
        }
      }
    }
    __syncthreads();
    const int b = panel >> 4, n0g = (panel & 15) * 64, cb = n0 - 512;
#pragma unroll
    for (int it = 0; it < 16; ++it) {
      const int rho = wv * 128 + it * 8 + (lane >> 3);  // 0..1023
      const int t = rho >> 8, c = rho & 255;
      const int nb = lane & 7;
      const uint4 d = *(const uint4*)&lds[t * 16384 + c * 64 + ((nb ^ (c & 7)) << 3)];
      *(uint4*)(job.out16b + (size_t)((t * 4 + b) * 512 + cb + c) * 1024 + n0g + nb * 8) = d;
    }
  } else {
#pragma unroll
    for (int i = 0; i < 4; ++i)
#pragma unroll
      for (int r = 0; r < 4; ++r) {
        unsigned short* prow = job.out16 + (size_t)(rbase + 16 * i + r) * job.ldc + n0 + wn * 128 + r15;
#pragma unroll
        for (int j = 0; j < 8; ++j) prow[j * 16] = f2bf(acc[i][j][r] * scl[j] + sft[j]);
      }
  }
}

// ---------------------------------------------------------------------------
// 128x256 GEMM (v/proj): K=512 fixed (NT=16). 8 waves (2Mx4N), wave 64x64.
// LDS: 4 bufs x 384 rows x 64B = 96KB. 3 gloads/wave/tile, vmcnt(3) steady.
// ---------------------------------------------------------------------------
__global__ __launch_bounds__(512, 2) void gemm_bn128(Job2 job) {
  const int xcd = blockIdx.x & 7, slot = blockIdx.x >> 3;
  const int panel = xcd + 8 * (slot >> 1);     // 0..127
  const int m0 = panel * 128;
  const int n0 = (slot & 1) * 256;

  const int tid = threadIdx.x;
  const int wv = tid >> 6, lane = tid & 63;
  const int wm = wv >> 2, wn = wv & 3;         // 2M x 4N, wave 64x64

  __shared__ unsigned short ABS[4][384 * 32];  // 96 KB

  const unsigned short* src[3];
#pragma unroll
  for (int g = 0; g < 3; ++g) {
    const int row = wv * 48 + g * 16 + (lane >> 2);
    const int ulog = (lane & 3) ^ (row & 3);
    src[g] = (row < 128) ? job.A + (size_t)(m0 + row) * job.lda + ulog * 8
                         : job.w + (size_t)(n0 + row - 128) * job.ldb + ulog * 8;
  }

#define ISSUE1(T_, BUF_) do {                                                \
    const int k0_ = (T_) << 5;                                               \
    _Pragma("unroll")                                                        \
    for (int g_ = 0; g_ < 3; ++g_)                                           \
      GLOAD16(src[g_] + k0_, &ABS[BUF_][(wv * 48 + g_ * 16) * 32]);          \
  } while (0)

  const int r15 = lane & 15;
  const int uoff = ((lane >> 4) ^ (r15 & 3)) << 3;
  const int arow0 = (wm * 64 + r15) * 32 + uoff;
  const int brow0 = (128 + wn * 64 + r15) * 32 + uoff;

  bf16x8 AX[4], BX[4], AY[4], BY[4];
#define RD1(BUF_, A_, B_) do {                                               \
    const unsigned short* lb_ = &ABS[BUF_][0];                               \
    _Pragma("unroll")                                                        \
    for (int i_ = 0; i_ < 4; ++i_) A_[i_] = *(const bf16x8*)(lb_ + arow0 + i_ * 512); \
    _Pragma("unroll")                                                        \
    for (int j_ = 0; j_ < 4; ++j_) B_[j_] = *(const bf16x8*)(lb_ + brow0 + j_ * 512); \
  } while (0)

#define MF1(A_, B_) do {                                                     \
    __builtin_amdgcn_s_setprio(1);                                           \
    _Pragma("unroll")                                                        \
    for (int i_ = 0; i_ < 4; ++i_)                                           \
    _Pragma("unroll")                                                        \
      for (int j_ = 0; j_ < 4; ++j_)                                         \
        acc[i_][j_] = __builtin_amdgcn_mfma_f32_16x16x32_bf16(A_[i_], B_[j_], acc[i_][j_], 0, 0, 0); \
    __builtin_amdgcn_s_setprio(0);                                           \
  } while (0)

#define MB1(N_) do {                                                         \
    asm volatile("s_waitcnt vmcnt(" #N_ ")" ::: "memory");                   \
    __builtin_amdgcn_s_barrier();                                            \
    __builtin_amdgcn_sched_barrier(0);                                       \
  } while (0)

  floatx4 acc[4][4];
#pragma unroll
  for (int i = 0; i < 4; ++i)
#pragma unroll
    for (int j = 0; j < 4; ++j) acc[i][j] = floatx4{0.f, 0.f, 0.f, 0.f};

  ISSUE1(0, 0); ISSUE1(1, 1); ISSUE1(2, 2);
  asm volatile("s_waitcnt vmcnt(6)" ::: "memory");
  __builtin_amdgcn_s_barrier();
  __builtin_amdgcn_sched_barrier(0);
  RD1(0, AX, BX);

#pragma unroll 1
  for (int kt = 0; kt < 12; kt += 2) {
    MB1(3); ISSUE1(kt + 3, (kt + 3) & 3); RD1((kt + 1) & 3, AY, BY); MF1(AX, BX);
    MB1(3); ISSUE1(kt + 4, (kt + 4) & 3); RD1((kt + 2) & 3, AX, BX); MF1(AY, BY);
  }
  MB1(3); ISSUE1(15, 3); RD1(1, AY, BY); MF1(AX, BX);   // slot 12
  MB1(3); RD1(2, AX, BX); MF1(AY, BY);                  // slot 13
  MB1(0); RD1(3, AY, BY); MF1(AX, BX);                  // slot 14
  MF1(AY, BY);                                          // slot 15

  // ---- epilogue
  float scl[4], sft[4];
#pragma unroll
  for (int j = 0; j < 4; ++j) {
    const int c = n0 + wn * 64 + j * 16 + r15;
    scl[j] = job.scl[c];
    sft[j] = job.sft[c];
  }
  const int rbase = m0 + wm * 64 + (lane >> 4) * 4;

  if (job.epi == 4) {
    // v: BN -> bf16 -> LDS [4t][256c][32n] (swizzled) -> vtr [t,b,c,n]
    __syncthreads();
    unsigned short* lds = &ABS[0][0];
    const int gq = lane >> 4;
#pragma unroll
    for (int i = 0; i < 4; ++i) {
      const int n_loc = wm * 16 + 4 * i + gq;          // 0..31
#pragma unroll
      for (int j = 0; j < 4; ++j) {
        const int c_loc = wn * 64 + j * 16 + r15;      // 0..255
        const int colbase = c_loc * 32 + (n_loc ^ (((c_loc >> 2) & 3) << 3));
#pragma unroll
        for (int r = 0; r < 4; ++r)
          lds[r * 8192 + colbase] = f2bf(acc[i][j][r] * scl[j] + sft[j]);
      }
    }
    __syncthreads();
    const int b = panel >> 5, n0g = (panel & 31) * 32;
#pragma unroll
    for (int it = 0; it < 8; ++it) {
      const int rho = wv * 128 + it * 16 + (lane >> 2); // 0..1023
      const int t = rho >> 8, c = rho & 255;
      const int nb = lane & 3;
      const uint4 d = *(const uint4*)&lds[t * 8192 + c * 32 + ((nb ^ ((c >> 2) & 3)) << 3)];
      *(uint4*)(job.out16b + (size_t)((t * 4 + b) * 512 + n0 + c) * 1024 + n0g + nb * 8) = d;
    }
  } else {
    // proj: f32 out, un-permute m' -> [t,b,n,c]
#pragma unroll
    for (int i = 0; i < 4; ++i)
#pragma unroll
      for (int r = 0; r < 4; ++r) {
        const int mp = rbase + 16 * i + r;
        const int t = mp & 3, bn = mp >> 2;
        const int mstd = (((t << 2) | (bn >> 10)) << 10) | (bn & 1023);
        float* prow = job.out32 + (size_t)mstd * 512 + n0 + wn * 64 + r15;
#pragma unroll
        for (int j = 0; j < 4; ++j) prow[j * 16] = acc[i][j][r] * scl[j] + sft[j];
      }
  }
}

// ---------------------------------------------------------------------------
__global__ __launch_bounds__(256) void kv_gemm(const unsigned short* __restrict__ ktr,
                                               const unsigned short* __restrict__ vtr,
                                               float* __restrict__ kvp) {
  const int bid = blockIdx.x;
  const int head = bid >> 1;
  const int mh = bid & 1;
  const int tb = head >> 3;
  const int h = head & 7;
  const int wv = threadIdx.x >> 6, lane = threadIdx.x & 63;
  const int m0 = mh * 512 + wv * 128;
  const size_t cbase = (size_t)tb * C_ + h * 64;
  const int rsel = lane & 15, koff = (lane >> 4) * 8;

  floatx4 acc[4][4];
#pragma unroll
  for (int i = 0; i < 4; ++i)
#pragma unroll
    for (int j = 0; j < 4; ++j) acc[i][j] = floatx4{0.f, 0.f, 0.f, 0.f};

#pragma unroll
  for (int s = 0; s < 4; ++s) {
    const int m = m0 + s * 32 + koff;
    bf16x8 a[4], b[4];
#pragma unroll
    for (int dt = 0; dt < 4; ++dt)
      a[dt] = *(const bf16x8*)(ktr + (cbase + dt * 16 + rsel) * N_ + m);
#pragma unroll
    for (int et = 0; et < 4; ++et)
      b[et] = *(const bf16x8*)(vtr + (cbase + et * 16 + rsel) * N_ + m);
#pragma unroll
    for (int dt = 0; dt < 4; ++dt)
#pragma unroll
      for (int et = 0; et < 4; ++et)
        acc[dt][et] = __builtin_amdgcn_mfma_f32_16x16x32_bf16(a[dt], b[et], acc[dt][et], 0, 0, 0);
  }

  float* outp = kvp + ((size_t)head * 8 + mh * 4 + wv) * 4096;
  const int dbase = (lane >> 4) * 4;
  const int e0 = lane & 15;
#pragma unroll
  for (int dt = 0; dt < 4; ++dt)
#pragma unroll
    for (int et = 0; et < 4; ++et)
#pragma unroll
      for (int r = 0; r < 4; ++r)
        outp[(dt * 16 + dbase + r) * 64 + et * 16 + e0] = acc[dt][et][r];
}

__global__ __launch_bounds__(256) void kv_reduce(const float* __restrict__ kvp,
                                                 unsigned short* __restrict__ kvt) {
  const int gid = blockIdx.x * 256 + threadIdx.x;
  const int idx4 = gid * 4;
  const int head = idx4 >> 12;
  const int rem = idx4 & 4095;
  const int e = rem >> 6, d0 = rem & 63;
  const float* p = kvp + (size_t)head * 8 * 4096;
  unsigned short rr[4];
#pragma unroll
  for (int j = 0; j < 4; ++j) {
    float s = 0.f;
#pragma unroll
    for (int pp = 0; pp < 8; ++pp) s += p[pp * 4096 + (d0 + j) * 64 + e];
    rr[j] = f2bf(0.125f * s);
  }
  uint2 o;
  o.x = (unsigned)rr[0] | ((unsigned)rr[1] << 16);
  o.y = (unsigned)rr[2] | ((unsigned)rr[3] << 16);
  *(uint2*)(kvt + idx4) = o;
}

// O rows in m' layout: row(n;t,b) = ((b<<10|n)<<2)|t
__global__ __launch_bounds__(256) void av_gemm(const unsigned short* __restrict__ qs,
                                               const unsigned short* __restrict__ kvt,
                                               unsigned short* __restrict__ obuf) {
  const int bx = blockIdx.x;
  const int tb = bx >> 3, nt = bx & 7;
  const int t = tb >> 2, b = tb & 3;
  const int wv = threadIdx.x >> 6, lane = threadIdx.x & 63;
  const int n0 = nt * 128 + wv * 32;
  const int rsel = lane & 15, koff = (lane >> 4) * 8;

#pragma unroll 1
  for (int h = 0; h < H_; ++h) {
    floatx4 acc[2][4];
#pragma unroll
    for (int i = 0; i < 2; ++i)
#pragma unroll
      for (int j = 0; j < 4; ++j) acc[i][j] = floatx4{0.f, 0.f, 0.f, 0.f};
    const unsigned short* kvh = kvt + ((size_t)tb * 8 + h) * 4096;
#pragma unroll
    for (int s = 0; s < 2; ++s) {
      bf16x8 a[2], bv[4];
#pragma unroll
      for (int i = 0; i < 2; ++i) {
        const int n = n0 + i * 16 + rsel;
        a[i] = *(const bf16x8*)(qs + (size_t)((((b << 10) | n) << 2) | t) * 512 + h * 64 + s * 32 + koff);
      }
#pragma unroll
      for (int et = 0; et < 4; ++et)
        bv[et] = *(const bf16x8*)(kvh + (et * 16 + rsel) * 64 + s * 32 + koff);
#pragma unroll
      for (int i = 0; i < 2; ++i)
#pragma unroll
        for (int et = 0; et < 4; ++et)
          acc[i][et] = __builtin_amdgcn_mfma_f32_16x16x32_bf16(a[i], bv[et], acc[i][et], 0, 0, 0);
    }
#pragma unroll
    for (int i = 0; i < 2; ++i)
#pragma unroll
      for (int et = 0; et < 4; ++et)
#pragma unroll
        for (int r = 0; r < 4; ++r) {
          const int n = n0 + i * 16 + (lane >> 4) * 4 + r;
          obuf[(size_t)((((b << 10) | n) << 2) | t) * 512 + h * 64 + et * 16 + rsel] = f2bf(acc[i][et][r]);
        }
  }
}

// ---------------------------------------------------------------------------
extern "C" void kernel_launch(void* const* d_in, const int* in_sizes, int n_in,
                              void* d_out, int out_size, void* d_ws, size_t ws_size,
                              hipStream_t stream) {
  const float* x  = (const float*)d_in[0];
  const float* qw = (const float*)d_in[2];
  const float* kw = (const float*)d_in[8];
  const float* vw = (const float*)d_in[14];
  const float* pw = (const float*)d_in[20];

  char* ws = (char*)d_ws;
  unsigned short* X2   = (unsigned short*)(ws + 0);            // 32 MB [m'][1024]
  unsigned short* Wqk3 = (unsigned short*)(ws + 33554432ull);  // 3 MB
  unsigned short* Wvb  = (unsigned short*)(ws + 36700160ull);  // 0.5 MB
  unsigned short* Wpb  = (unsigned short*)(ws + 37224448ull);  // 0.5 MB
  float*          scl  = (float*)(ws + 37748736ull);           // 8 KB
  float*          sft  = (float*)(ws + 37756928ull);           // 8 KB
  unsigned short* qsb  = (unsigned short*)(ws + 41943040ull);  // 16 MB [m'][512]
  unsigned short* ktr  = (unsigned short*)(ws + 58720256ull);  // 16 MB [t,b,c,n]
  unsigned short* vtr  = (unsigned short*)(ws + 75497472ull);  // 16 MB [t,b,c,n]
  float*          kvp  = (float*)(ws + 92274688ull);           // 16 MB
  unsigned short* kvt  = (unsigned short*)(ws + 109051904ull); // 1 MB
  unsigned short* ob   = (unsigned short*)(ws + 110100480ull); // 16 MB [m'][512]

  prep_split_x<<<dim3(M_ * C_ / 4 / 256), 256, 0, stream>>>(x, X2, M_ * C_);
  prep_weights<<<dim3(C_ * C_ / 4 / 256, 1, 4), 256, 0, stream>>>(qw, kw, vw, pw, Wqk3, Wvb, Wpb);

  BnParams bp;
  bp.p[0]=(const float*)d_in[3];  bp.p[1]=(const float*)d_in[4];  bp.p[2]=(const float*)d_in[5];  bp.p[3]=(const float*)d_in[6];  bp.p[4]=(const float*)d_in[7];
  bp.p[5]=(const float*)d_in[9];  bp.p[6]=(const float*)d_in[10]; bp.p[7]=(const float*)d_in[11]; bp.p[8]=(const float*)d_in[12]; bp.p[9]=(const float*)d_in[13];
  bp.p[10]=(const float*)d_in[15];bp.p[11]=(const float*)d_in[16];bp.p[12]=(const float*)d_in[17];bp.p[13]=(const float*)d_in[18];bp.p[14]=(const float*)d_in[19];
  bp.p[15]=(const float*)d_in[21];bp.p[16]=(const float*)d_in[22];bp.p[17]=(const float*)d_in[23];bp.p[18]=(const float*)d_in[24];bp.p[19]=(const float*)d_in[25];
  bn_prep<<<dim3(8), 256, 0, stream>>>(bp, scl, sft);

  // qk GEMM: 64 panels x 4 n-tiles = 256 blocks; q->qsb, k->ktr (transposed)
  Job2 jqk{X2, 1024, Wqk3, 1536, 1536, 512, 2, scl, sft, nullptr, qsb, ktr};
  gemm_bn<<<dim3(256), 512, 0, stream>>>(jqk, 2);

  // v GEMM: 128 panels x 2 n-tiles = 256 blocks; -> vtr (transposed)
  Job2 jv{X2, 1024, Wvb, 512, 512, 512, 4, scl + 1024, sft + 1024, nullptr, nullptr, vtr};
  gemm_bn128<<<dim3(256), 512, 0, stream>>>(jv);

  kv_gemm<<<dim3(256), 256, 0, stream>>>(ktr, vtr, kvp);
  kv_reduce<<<dim3(512), 256, 0, stream>>>(kvp, kvt);
  av_gemm<<<dim3(128), 256, 0, stream>>>(qsb, kvt, ob);

  // proj GEMM: 128 panels x 2 n-tiles = 256 blocks; f32 un-permuted out
  Job2 jp{ob, 512, Wpb, 512, 512, 512, 3, scl + 1536, sft + 1536, (float*)d_out, nullptr, nullptr};
  gemm_bn128<<<dim3(256), 512, 0, stream>>>(jp);
}

// Round 8
// 126.238 us; speedup vs baseline: 1.6194x; 1.1175x over previous
//
#include <hip/hip_runtime.h>

// SSA forward, f32 I/O:
//   q = heads(lif(bn(x Wq^T))), k = heads(lif(bn(x Wk^T))), v = heads(bn(x Wv^T))
//   o = 0.125 * q @ (k^T v)   (no softmax -> associativity), out = bn(o Wp^T)
// Q/K GEMMs: 3-term bf16 split (xh*wh + xl*wh + xh*wl) for ~f32 accuracy.
// Row permutation m' = ((b*N+n)*T + t): LIF fused in GEMM epilogue; k/v
// written directly transposed [t,b,c,n] via LDS-transpose epilogue.
// 6 dispatches: prep_all, qk-GEMM(256x256), v-GEMM(128x256), kv(+reduce),
// av(256 blocks), proj-GEMM. GEMM cores register-pipelined (frozen r5-r7).

#define T_ 4
#define B_ 4
#define N_ 1024
#define C_ 512
#define H_ 8
#define M_ (T_*B_*N_)   // 16384

typedef __bf16 bf16x8 __attribute__((ext_vector_type(8)));
typedef float  floatx4 __attribute__((ext_vector_type(4)));

__device__ __forceinline__ float bf2f(unsigned short u) {
  union { unsigned int i; float f; } v; v.i = ((unsigned int)u) << 16; return v.f;
}
__device__ __forceinline__ unsigned short f2bf(float f) {
  unsigned int x = __float_as_uint(f);
  return (unsigned short)((x + 0x7fffu + ((x >> 16) & 1u)) >> 16);  // RNE
}

#define GLOAD16(gaddr, ldsbase) \
  __builtin_amdgcn_global_load_lds((__attribute__((address_space(1))) void*)(gaddr), \
                                   (__attribute__((address_space(3))) void*)(ldsbase), 16, 0, 0)

struct BnParams { const float* p[20]; };
struct PrepArgs {
  const float *x, *qw, *kw, *vw, *pw;
  unsigned short *X2, *Wqk3, *Wvb, *Wpb;
  float *scl, *sft;
  BnParams bp;
};

// One dispatch: blocks [0,8192) x-split, [8192,9216) weights, [9216,9224) bn.
__global__ __launch_bounds__(256) void prep_all(PrepArgs P) {
  const int bid = blockIdx.x;
  if (bid < 8192) {
    // x [t,b,n,c] f32 -> X2 [m'][1024] bf16 2-seg [hi|lo], m' = ((b*N+n)*T+t)
    const int idx = (bid * 256 + threadIdx.x) * 4;
    const float4 v = *(const float4*)(P.x + idx);
    const int m = idx >> 9, k = idx & 511;
    const int t = m >> 12, b = (m >> 10) & 3, n = m & 1023;
    const int mp = (((b << 10) | n) << 2) | t;
    const size_t base = (size_t)mp * 1024 + k;
    float vv[4] = {v.x, v.y, v.z, v.w};
    unsigned short h[4], l[4];
#pragma unroll
    for (int j = 0; j < 4; ++j) { h[j] = f2bf(vv[j]); l[j] = f2bf(vv[j] - bf2f(h[j])); }
    *(ushort4*)(P.X2 + base) = ushort4{h[0], h[1], h[2], h[3]};
    *(ushort4*)(P.X2 + base + 512) = ushort4{l[0], l[1], l[2], l[3]};
  } else if (bid < 9216) {
    const int z = (bid - 8192) >> 8;
    const int idx = ((((bid - 8192) & 255) * 256) + threadIdx.x) * 4;
    const float* src = (z == 0) ? P.qw : (z == 1) ? P.kw : (z == 2) ? P.vw : P.pw;
    const float4 v = *(const float4*)(src + idx);
    if (z >= 2) {
      unsigned short* dst = (z == 2) ? P.Wvb : P.Wpb;
      *(ushort4*)(dst + idx) = ushort4{f2bf(v.x), f2bf(v.y), f2bf(v.z), f2bf(v.w)};
      return;
    }
    const int row = idx >> 9, k = idx & 511;
    unsigned short* dst = P.Wqk3 + (size_t)(z * 512) * 1536;
    const size_t base = (size_t)row * 1536 + k;
    float vv[4] = {v.x, v.y, v.z, v.w};
    unsigned short h[4], l[4];
#pragma unroll
    for (int j = 0; j < 4; ++j) { h[j] = f2bf(vv[j]); l[j] = f2bf(vv[j] - bf2f(h[j])); }
    ushort4 hi{h[0], h[1], h[2], h[3]};
    *(ushort4*)(dst + base) = hi;
    *(ushort4*)(dst + base + 512) = hi;
    *(ushort4*)(dst + base + 1024) = ushort4{l[0], l[1], l[2], l[3]};
  } else {
    const int o = (bid - 9216) * 256 + threadIdx.x;  // 0..2047
    const int grp = o >> 9, ci = o & 511;
    const float s = P.bp.p[grp * 5 + 1][ci] * rsqrtf(P.bp.p[grp * 5 + 4][ci] + 1e-5f);
    P.scl[o] = s;
    P.sft[o] = (P.bp.p[grp * 5 + 0][ci] - P.bp.p[grp * 5 + 3][ci]) * s + P.bp.p[grp * 5 + 2][ci];
  }
}

struct Job2 {
  const unsigned short* A; int lda;
  const unsigned short* w; int ldb;
  int K, ldc, epi;  // epi: 2=qk dual (q->qsb, k->LDS-transpose->ktr)
                    //      3=f32 unpermuted, 4=bf16 LDS-transpose (v->vtr)
  const float* scl; const float* sft;
  float* out32; unsigned short* out16; unsigned short* out16b;
};

// ---------------------------------------------------------------------------
// 256x256 GEMM (qk). Core frozen from r5-r7.
// ---------------------------------------------------------------------------
__global__ __launch_bounds__(512, 2) void gemm_bn(Job2 job, int lntile) {
  const int xcd = blockIdx.x & 7, slot = blockIdx.x >> 3;
  const int ntm1 = (1 << lntile) - 1;
  const int panel = xcd + 8 * (slot >> lntile);
  const int m0 = panel * 256;
  const int n0 = (slot & ntm1) * 256;

  const int tid = threadIdx.x;
  const int wv = tid >> 6, lane = tid & 63;
  const int wm = wv >> 1, wn = wv & 1;
  const int NT = job.K >> 5;

  __shared__ unsigned short AB[4][256 * 64];

  const int rloc = lane >> 3;
  const int ulog = (lane & 7) ^ rloc;
  const bool isA = ulog < 4;
  const unsigned short* bq[4];
#pragma unroll
  for (int q = 0; q < 4; ++q) {
    const int row = wv * 32 + q * 8 + rloc;
    bq[q] = isA ? job.A + (size_t)(m0 + row) * job.lda + ulog * 8
                : job.w + (size_t)(n0 + row) * job.ldb + (ulog - 4) * 8;
  }

#define ISSUE(T_, BUF_) do {                                                 \
    const int t_ = (T_);                                                     \
    const int off_ = isA ? ((t_ < 32 ? t_ : t_ - 32) << 5) : (t_ << 5);      \
    _Pragma("unroll")                                                        \
    for (int q = 0; q < 4; ++q)                                              \
      GLOAD16(bq[q] + off_, &AB[BUF_][(wv * 32 + q * 8) * 64]);              \
  } while (0)

  const int r15 = lane & 15;
  const int apos = (lane >> 4) ^ (lane & 7);
  const int bpos = (4 | (lane >> 4)) ^ (lane & 7);
  const int aoff = (wm * 64 + r15) * 64 + apos * 8;
  const int boff = (wn * 128 + r15) * 64 + bpos * 8;

  bf16x8 A0[4], A1[4], L0[4], L1[4], Hh[4];

#define RD_ALO(BUF_, AX, LX) do {                                            \
    const unsigned short* lb_ = &AB[BUF_][0];                                \
    _Pragma("unroll")                                                        \
    for (int i_ = 0; i_ < 4; ++i_) AX[i_] = *(const bf16x8*)(lb_ + aoff + i_ * 1024); \
    _Pragma("unroll")                                                        \
    for (int j_ = 0; j_ < 4; ++j_) LX[j_] = *(const bf16x8*)(lb_ + boff + j_ * 1024); \
  } while (0)

#define RD_HI(BUF_) do {                                                     \
    const unsigned short* lb_ = &AB[BUF_][0];                                \
    _Pragma("unroll")                                                        \
    for (int j_ = 0; j_ < 4; ++j_) Hh[j_] = *(const bf16x8*)(lb_ + boff + (4 + j_) * 1024); \
  } while (0)

#define MF_LO(AX, LX) do {                                                   \
    __builtin_amdgcn_s_setprio(1);                                           \
    _Pragma("unroll")                                                        \
    for (int i_ = 0; i_ < 4; ++i_)                                           \
    _Pragma("unroll")                                                        \
      for (int j_ = 0; j_ < 4; ++j_)                                         \
        acc[i_][j_] = __builtin_amdgcn_mfma_f32_16x16x32_bf16(AX[i_], LX[j_], acc[i_][j_], 0, 0, 0); \
    __builtin_amdgcn_s_setprio(0);                                           \
  } while (0)

#define MF_HI(AX) do {                                                       \
    __builtin_amdgcn_s_setprio(1);                                           \
    _Pragma("unroll")                                                        \
    for (int i_ = 0; i_ < 4; ++i_)                                           \
    _Pragma("unroll")                                                        \
      for (int j_ = 0; j_ < 4; ++j_)                                         \
        acc[i_][4 + j_] = __builtin_amdgcn_mfma_f32_16x16x32_bf16(AX[i_], Hh[j_], acc[i_][4 + j_], 0, 0, 0); \
    __builtin_amdgcn_s_setprio(0);                                           \
  } while (0)

#define MIDBAR(N_) do {                                                      \
    asm volatile("s_waitcnt vmcnt(" #N_ ")" ::: "memory");                   \
    __builtin_amdgcn_s_barrier();                                            \
    __builtin_amdgcn_sched_barrier(0);                                       \
  } while (0)

#define SLOT_I(KT_, BC_, BN_, AX, LX, AY, LY) do {                           \
    RD_HI(BC_); MF_LO(AX, LX);                                               \
    MIDBAR(4);                                                               \
    ISSUE((KT_) + 3, (BC_ + 3) & 3);                                         \
    RD_ALO(BN_, AY, LY); MF_HI(AX);                                          \
  } while (0)

  floatx4 acc[4][8];
#pragma unroll
  for (int i = 0; i < 4; ++i)
#pragma unroll
    for (int j = 0; j < 8; ++j) acc[i][j] = floatx4{0.f, 0.f, 0.f, 0.f};

  ISSUE(0, 0); ISSUE(1, 1); ISSUE(2, 2);
  asm volatile("s_waitcnt vmcnt(4)" ::: "memory");
  __builtin_amdgcn_s_barrier();
  __builtin_amdgcn_sched_barrier(0);
  RD_ALO(0, A0, L0);

  const int NG = (NT - 4) >> 2;
  for (int g = 0; g < NG; ++g) {
    const int g4 = g << 2;
    SLOT_I(g4 + 0, 0, 1, A0, L0, A1, L1);
    SLOT_I(g4 + 1, 1, 2, A1, L1, A0, L0);
    SLOT_I(g4 + 2, 2, 3, A0, L0, A1, L1);
    SLOT_I(g4 + 3, 3, 0, A1, L1, A0, L0);
  }
  SLOT_I(NT - 4, 0, 1, A0, L0, A1, L1);
  RD_HI(1); MF_LO(A1, L1); MIDBAR(4); RD_ALO(2, A0, L0); MF_HI(A1);
  RD_HI(2); MF_LO(A0, L0); MIDBAR(0); RD_ALO(3, A1, L1); MF_HI(A0);
  RD_HI(3); MF_LO(A1, L1); MF_HI(A1);

  // ---- epilogue
  float scl[8], sft[8];
#pragma unroll
  for (int j = 0; j < 8; ++j) {
    const int c = n0 + wn * 128 + j * 16 + r15;
    scl[j] = job.scl[c];
    sft[j] = job.sft[c];
  }
  const int rbase = m0 + wm * 64 + (lane >> 4) * 4;

  if (job.epi == 2 && n0 < 512) {
    // q half: BN -> in-register LIF -> qsb [m'][512]
    const int cb = n0 + wn * 128 + r15;
#pragma unroll
    for (int i = 0; i < 4; ++i) {
      unsigned short spk[4][8];
#pragma unroll
      for (int j = 0; j < 8; ++j) {
        float vme = 0.f;
#pragma unroll
        for (int r = 0; r < 4; ++r) {
          const float y = acc[i][j][r] * scl[j] + sft[j];
          vme += (y - vme) * 0.5f;
          const bool sp = vme >= 1.0f;
          spk[r][j] = sp ? (unsigned short)0x3F80 : (unsigned short)0;
          if (sp) vme = 0.f;
        }
      }
#pragma unroll
      for (int r = 0; r < 4; ++r) {
        unsigned short* prow = job.out16 + (size_t)(rbase + 16 * i + r) * 512 + cb;
#pragma unroll
        for (int j = 0; j < 8; ++j) prow[j * 16] = spk[r][j];
      }
    }
  } else if (job.epi == 2) {
    // k half: BN -> LIF -> LDS [4t][256c][64n] (swizzled) -> ktr [t,b,c,n]
    __syncthreads();
    unsigned short* lds = &AB[0][0];
    const int gq = lane >> 4;
#pragma unroll
    for (int i = 0; i < 4; ++i) {
      const int n_loc = wm * 16 + 4 * i + gq;
#pragma unroll
      for (int j = 0; j < 8; ++j) {
        const int c_loc = wn * 128 + j * 16 + r15;
        const int colbase = c_loc * 64 + (n_loc ^ ((c_loc & 7) << 3));
        float vme = 0.f;
#pragma unroll
        for (int r = 0; r < 4; ++r) {
          const float y = acc[i][j][r] * scl[j] + sft[j];
          vme += (y - vme) * 0.5f;
          const bool sp = vme >= 1.0f;
          lds[r * 16384 + colbase] = sp ? (unsigned short)0x3F80 : (unsigned short)0;
          if (sp) vme = 0.f;
        }
      }
    }
    __syncthreads();
    const int b = panel >> 4, n0g = (panel & 15) * 64, cb = n0 - 512;
#pragma unroll
    for (int it = 0; it < 16; ++it) {
      const int rho = wv * 128 + it * 8 + (lane >> 3);
      const int t = rho >> 8, c = rho & 255;
      const int nb = lane & 7;
      const uint4 d = *(const uint4*)&lds[t * 16384 + c * 64 + ((nb ^ (c & 7)) << 3)];
      *(uint4*)(job.out16b + (size_t)((t * 4 + b) * 512 + cb + c) * 1024 + n0g + nb * 8) = d;
    }
  } else {
#pragma unroll
    for (int i = 0; i < 4; ++i)
#pragma unroll
      for (int r = 0; r < 4; ++r) {
        unsigned short* prow = job.out16 + (size_t)(rbase + 16 * i + r) * job.ldc + n0 + wn * 128 + r15;
#pragma unroll
        for (int j = 0; j < 8; ++j) prow[j * 16] = f2bf(acc[i][j][r] * scl[j] + sft[j]);
      }
  }
}

// ---------------------------------------------------------------------------
// 128x256 GEMM (v/proj): K=512 (NT=16). Frozen from r7.
// ---------------------------------------------------------------------------
__global__ __launch_bounds__(512, 2) void gemm_bn128(Job2 job) {
  const int xcd = blockIdx.x & 7, slot = blockIdx.x >> 3;
  const int panel = xcd + 8 * (slot >> 1);
  const int m0 = panel * 128;
  const int n0 = (slot & 1) * 256;

  const int tid = threadIdx.x;
  const int wv = tid >> 6, lane = tid & 63;
  const int wm = wv >> 2, wn = wv & 3;

  __shared__ unsigned short ABS[4][384 * 32];

  const unsigned short* src[3];
#pragma unroll
  for (int g = 0; g < 3; ++g) {
    const int row = wv * 48 + g * 16 + (lane >> 2);
    const int ulog = (lane & 3) ^ (row & 3);
    src[g] = (row < 128) ? job.A + (size_t)(m0 + row) * job.lda + ulog * 8
                         : job.w + (size_t)(n0 + row - 128) * job.ldb + ulog * 8;
  }

#define ISSUE1(T_, BUF_) do {                                                \
    const int k0_ = (T_) << 5;                                               \
    _Pragma("unroll")                                                        \
    for (int g_ = 0; g_ < 3; ++g_)                                           \
      GLOAD16(src[g_] + k0_, &ABS[BUF_][(wv * 48 + g_ * 16) * 32]);          \
  } while (0)

  const int r15 = lane & 15;
  const int uoff = ((lane >> 4) ^ (r15 & 3)) << 3;
  const int arow0 = (wm * 64 + r15) * 32 + uoff;
  const int brow0 = (128 + wn * 64 + r15) * 32 + uoff;

  bf16x8 AX[4], BX[4], AY[4], BY[4];
#define RD1(BUF_, A_, B_) do {                                               \
    const unsigned short* lb_ = &ABS[BUF_][0];                               \
    _Pragma("unroll")                                                        \
    for (int i_ = 0; i_ < 4; ++i_) A_[i_] = *(const bf16x8*)(lb_ + arow0 + i_ * 512); \
    _Pragma("unroll")                                                        \
    for (int j_ = 0; j_ < 4; ++j_) B_[j_] = *(const bf16x8*)(lb_ + brow0 + j_ * 512); \
  } while (0)

#define MF1(A_, B_) do {                                                     \
    __builtin_amdgcn_s_setprio(1);                                           \
    _Pragma("unroll")                                                        \
    for (int i_ = 0; i_ < 4; ++i_)                                           \
    _Pragma("unroll")                                                        \
      for (int j_ = 0; j_ < 4; ++j_)                                         \
        acc[i_][j_] = __builtin_amdgcn_mfma_f32_16x16x32_bf16(A_[i_], B_[j_], acc[i_][j_], 0, 0, 0); \
    __builtin_amdgcn_s_setprio(0);                                           \
  } while (0)

#define MB1(N_) do {                                                         \
    asm volatile("s_waitcnt vmcnt(" #N_ ")" ::: "memory");                   \
    __builtin_amdgcn_s_barrier();                                            \
    __builtin_amdgcn_sched_barrier(0);                                       \
  } while (0)

  floatx4 acc[4][4];
#pragma unroll
  for (int i = 0; i < 4; ++i)
#pragma unroll
    for (int j = 0; j < 4; ++j) acc[i][j] = floatx4{0.f, 0.f, 0.f, 0.f};

  ISSUE1(0, 0); ISSUE1(1, 1); ISSUE1(2, 2);
  asm volatile("s_waitcnt vmcnt(6)" ::: "memory");
  __builtin_amdgcn_s_barrier();
  __builtin_amdgcn_sched_barrier(0);
  RD1(0, AX, BX);

#pragma unroll 1
  for (int kt = 0; kt < 12; kt += 2) {
    MB1(3); ISSUE1(kt + 3, (kt + 3) & 3); RD1((kt + 1) & 3, AY, BY); MF1(AX, BX);
    MB1(3); ISSUE1(kt + 4, (kt + 4) & 3); RD1((kt + 2) & 3, AX, BX); MF1(AY, BY);
  }
  MB1(3); ISSUE1(15, 3); RD1(1, AY, BY); MF1(AX, BX);
  MB1(3); RD1(2, AX, BX); MF1(AY, BY);
  MB1(0); RD1(3, AY, BY); MF1(AX, BX);
  MF1(AY, BY);

  // ---- epilogue
  float scl[4], sft[4];
#pragma unroll
  for (int j = 0; j < 4; ++j) {
    const int c = n0 + wn * 64 + j * 16 + r15;
    scl[j] = job.scl[c];
    sft[j] = job.sft[c];
  }
  const int rbase = m0 + wm * 64 + (lane >> 4) * 4;

  if (job.epi == 4) {
    __syncthreads();
    unsigned short* lds = &ABS[0][0];
    const int gq = lane >> 4;
#pragma unroll
    for (int i = 0; i < 4; ++i) {
      const int n_loc = wm * 16 + 4 * i + gq;
#pragma unroll
      for (int j = 0; j < 4; ++j) {
        const int c_loc = wn * 64 + j * 16 + r15;
        const int colbase = c_loc * 32 + (n_loc ^ (((c_loc >> 2) & 3) << 3));
#pragma unroll
        for (int r = 0; r < 4; ++r)
          lds[r * 8192 + colbase] = f2bf(acc[i][j][r] * scl[j] + sft[j]);
      }
    }
    __syncthreads();
    const int b = panel >> 5, n0g = (panel & 31) * 32;
#pragma unroll
    for (int it = 0; it < 8; ++it) {
      const int rho = wv * 128 + it * 16 + (lane >> 2);
      const int t = rho >> 8, c = rho & 255;
      const int nb = lane & 3;
      const uint4 d = *(const uint4*)&lds[t * 8192 + c * 32 + ((nb ^ ((c >> 2) & 3)) << 3)];
      *(uint4*)(job.out16b + (size_t)((t * 4 + b) * 512 + n0 + c) * 1024 + n0g + nb * 8) = d;
    }
  } else {
#pragma unroll
    for (int i = 0; i < 4; ++i)
#pragma unroll
      for (int r = 0; r < 4; ++r) {
        const int mp = rbase + 16 * i + r;
        const int t = mp & 3, bn = mp >> 2;
        const int mstd = (((t << 2) | (bn >> 10)) << 10) | (bn & 1023);
        float* prow = job.out32 + (size_t)mstd * 512 + n0 + wn * 64 + r15;
#pragma unroll
        for (int j = 0; j < 4; ++j) prow[j * 16] = acc[i][j][r] * scl[j] + sft[j];
      }
  }
}

// ---------------------------------------------------------------------------
// kv_gemm with fused reduction: 128 blocks = 1 head, 4 waves x 256 m,
// sequential barrier-ordered LDS reduce (deterministic), ->kvt bf16.
// ---------------------------------------------------------------------------
__global__ __launch_bounds__(256) void kv_gemm(const unsigned short* __restrict__ ktr,
                                               const unsigned short* __restrict__ vtr,
                                               unsigned short* __restrict__ kvt) {
  const int head = blockIdx.x;          // tb*8+h
  const int tb = head >> 3;
  const int h = head & 7;
  const int wv = threadIdx.x >> 6, lane = threadIdx.x & 63;
  const int m0 = wv * 256;
  const size_t cbase = (size_t)tb * C_ + h * 64;
  const int rsel = lane & 15, koff = (lane >> 4) * 8;

  floatx4 acc[4][4];
#pragma unroll
  for (int i = 0; i < 4; ++i)
#pragma unroll
    for (int j = 0; j < 4; ++j) acc[i][j] = floatx4{0.f, 0.f, 0.f, 0.f};

#pragma unroll
  for (int s = 0; s < 8; ++s) {
    const int m = m0 + s * 32 + koff;
    bf16x8 a[4], b[4];
#pragma unroll
    for (int dt = 0; dt < 4; ++dt)
      a[dt] = *(const bf16x8*)(ktr + (cbase + dt * 16 + rsel) * N_ + m);
#pragma unroll
    for (int et = 0; et < 4; ++et)
      b[et] = *(const bf16x8*)(vtr + (cbase + et * 16 + rsel) * N_ + m);
#pragma unroll
    for (int dt = 0; dt < 4; ++dt)
#pragma unroll
      for (int et = 0; et < 4; ++et)
        acc[dt][et] = __builtin_amdgcn_mfma_f32_16x16x32_bf16(a[dt], b[et], acc[dt][et], 0, 0, 0);
  }

  __shared__ float red[4096];           // [d][e]
  const int dbase = (lane >> 4) * 4;
  const int e0 = lane & 15;
#pragma unroll 1
  for (int w = 0; w < 4; ++w) {
    if (wv == w) {
#pragma unroll
      for (int dt = 0; dt < 4; ++dt)
#pragma unroll
        for (int et = 0; et < 4; ++et)
#pragma unroll
          for (int r = 0; r < 4; ++r) {
            const int o = (dt * 16 + dbase + r) * 64 + et * 16 + e0;
            red[o] = (w == 0) ? acc[dt][et][r] : red[o] + acc[dt][et][r];
          }
    }
    __syncthreads();
  }
  // kvt[head][e*64+d] = 0.125 * red[d*64+e]
  const int d = threadIdx.x & 63;
  const int eg = threadIdx.x >> 6;
#pragma unroll
  for (int j = 0; j < 16; ++j) {
    const int e = eg * 16 + j;
    kvt[(size_t)head * 4096 + e * 64 + d] = f2bf(0.125f * red[d * 64 + e]);
  }
}

// ---------------------------------------------------------------------------
// av: O rows in m' layout. 256 blocks = (tb, nt, h-half); 4 heads per block.
// ---------------------------------------------------------------------------
__global__ __launch_bounds__(256) void av_gemm(const unsigned short* __restrict__ qs,
                                               const unsigned short* __restrict__ kvt,
                                               unsigned short* __restrict__ obuf) {
  const int bx = blockIdx.x;            // 256
  const int tb = bx >> 4;
  const int sub = bx & 15;
  const int nt = sub >> 1;
  const int h0 = (sub & 1) * 4;
  const int t = tb >> 2, b = tb & 3;
  const int wv = threadIdx.x >> 6, lane = threadIdx.x & 63;
  const int n0 = nt * 128 + wv * 32;
  const int rsel = lane & 15, koff = (lane >> 4) * 8;

#pragma unroll 1
  for (int h = h0; h < h0 + 4; ++h) {
    floatx4 acc[2][4];
#pragma unroll
    for (int i = 0; i < 2; ++i)
#pragma unroll
      for (int j = 0; j < 4; ++j) acc[i][j] = floatx4{0.f, 0.f, 0.f, 0.f};
    const unsigned short* kvh = kvt + ((size_t)tb * 8 + h) * 4096;
#pragma unroll
    for (int s = 0; s < 2; ++s) {
      bf16x8 a[2], bv[4];
#pragma unroll
      for (int i = 0; i < 2; ++i) {
        const int n = n0 + i * 16 + rsel;
        a[i] = *(const bf16x8*)(qs + (size_t)((((b << 10) | n) << 2) | t) * 512 + h * 64 + s * 32 + koff);
      }
#pragma unroll
      for (int et = 0; et < 4; ++et)
        bv[et] = *(const bf16x8*)(kvh + (et * 16 + rsel) * 64 + s * 32 + koff);
#pragma unroll
      for (int i = 0; i < 2; ++i)
#pragma unroll
        for (int et = 0; et < 4; ++et)
          acc[i][et] = __builtin_amdgcn_mfma_f32_16x16x32_bf16(a[i], bv[et], acc[i][et], 0, 0, 0);
    }
#pragma unroll
    for (int i = 0; i < 2; ++i)
#pragma unroll
      for (int et = 0; et < 4; ++et)
#pragma unroll
        for (int r = 0; r < 4; ++r) {
          const int n = n0 + i * 16 + (lane >> 4) * 4 + r;
          obuf[(size_t)((((b << 10) | n) << 2) | t) * 512 + h * 64 + et * 16 + rsel] = f2bf(acc[i][et][r]);
        }
  }
}

// ---------------------------------------------------------------------------
extern "C" void kernel_launch(void* const* d_in, const int* in_sizes, int n_in,
                              void* d_out, int out_size, void* d_ws, size_t ws_size,
                              hipStream_t stream) {
  char* ws = (char*)d_ws;
  unsigned short* X2   = (unsigned short*)(ws + 0);            // 32 MB [m'][1024]
  unsigned short* Wqk3 = (unsigned short*)(ws + 33554432ull);  // 3 MB
  unsigned short* Wvb  = (unsigned short*)(ws + 36700160ull);  // 0.5 MB
  unsigned short* Wpb  = (unsigned short*)(ws + 37224448ull);  // 0.5 MB
  float*          scl  = (float*)(ws + 37748736ull);           // 8 KB
  float*          sft  = (float*)(ws + 37756928ull);           // 8 KB
  unsigned short* qsb  = (unsigned short*)(ws + 41943040ull);  // 16 MB [m'][512]
  unsigned short* ktr  = (unsigned short*)(ws + 58720256ull);  // 16 MB [t,b,c,n]
  unsigned short* vtr  = (unsigned short*)(ws + 75497472ull);  // 16 MB [t,b,c,n]
  unsigned short* kvt  = (unsigned short*)(ws + 92274688ull);  // 1 MB
  unsigned short* ob   = (unsigned short*)(ws + 93323264ull);  // 16 MB [m'][512]

  PrepArgs pa;
  pa.x  = (const float*)d_in[0];
  pa.qw = (const float*)d_in[2];
  pa.kw = (const float*)d_in[8];
  pa.vw = (const float*)d_in[14];
  pa.pw = (const float*)d_in[20];
  pa.X2 = X2; pa.Wqk3 = Wqk3; pa.Wvb = Wvb; pa.Wpb = Wpb;
  pa.scl = scl; pa.sft = sft;
  pa.bp.p[0]=(const float*)d_in[3];  pa.bp.p[1]=(const float*)d_in[4];  pa.bp.p[2]=(const float*)d_in[5];  pa.bp.p[3]=(const float*)d_in[6];  pa.bp.p[4]=(const float*)d_in[7];
  pa.bp.p[5]=(const float*)d_in[9];  pa.bp.p[6]=(const float*)d_in[10]; pa.bp.p[7]=(const float*)d_in[11]; pa.bp.p[8]=(const float*)d_in[12]; pa.bp.p[9]=(const float*)d_in[13];
  pa.bp.p[10]=(const float*)d_in[15];pa.bp.p[11]=(const float*)d_in[16];pa.bp.p[12]=(const float*)d_in[17];pa.bp.p[13]=(const float*)d_in[18];pa.bp.p[14]=(const float*)d_in[19];
  pa.bp.p[15]=(const float*)d_in[21];pa.bp.p[16]=(const float*)d_in[22];pa.bp.p[17]=(const float*)d_in[23];pa.bp.p[18]=(const float*)d_in[24];pa.bp.p[19]=(const float*)d_in[25];
  prep_all<<<dim3(9224), 256, 0, stream>>>(pa);

  Job2 jqk{X2, 1024, Wqk3, 1536, 1536, 512, 2, scl, sft, nullptr, qsb, ktr};
  gemm_bn<<<dim3(256), 512, 0, stream>>>(jqk, 2);

  Job2 jv{X2, 1024, Wvb, 512, 512, 512, 4, scl + 1024, sft + 1024, nullptr, nullptr, vtr};
  gemm_bn128<<<dim3(256), 512, 0, stream>>>(jv);

  kv_gemm<<<dim3(128), 256, 0, stream>>>(ktr, vtr, kvt);
  av_gemm<<<dim3(256), 256, 0, stream>>>(qsb, kvt, ob);

  Job2 jp{ob, 512, Wpb, 512, 512, 512, 3, scl + 1536, sft + 1536, (float*)d_out, nullptr, nullptr};
  gemm_bn128<<<dim3(256), 512, 0, stream>>>(jp);
}